// Round 18
// baseline (263.448 us; speedup 1.0000x reference)
//
#include <hip/hip_runtime.h>
#include <hip/hip_cooperative_groups.h>
#include <math.h>

#define NNODES 883
#define BB 8
#define DIMS_ 160
#define HID_ 320
#define PBB 1008                // padded rows per batch (patch offsets aligned to 16)
#define RMAX2 (BB*PBB)          // 8064 packed rows incl. padding
#define RMAXP (RMAX2+64)        // vt row stride
#define GXNUM (RMAX2/16)        // 504 row tiles

typedef __attribute__((ext_vector_type(8))) short short8v;   // 8 bf16 in 4 VGPRs
typedef __attribute__((ext_vector_type(4))) float fx4;
typedef __attribute__((ext_vector_type(4))) unsigned short ushort4v;

__device__ __forceinline__ unsigned short f2bf(float f) {
  unsigned int u = __float_as_uint(f);
  u = (u + 0x7fffu + ((u >> 16) & 1u)) >> 16;   // RNE
  return (unsigned short)u;
}
__device__ __forceinline__ float bf2f(unsigned short u) {
  return __uint_as_float(((unsigned int)u) << 16);
}
__device__ __forceinline__ float gelu_f(float v) {
  return 0.5f*v*(1.f + erff(v*0.70710678118654752f));
}

// ---------------- cheap pf zeroing ----------------
__global__ __launch_bounds__(256)
void zero_pf(float4* __restrict__ p, int n4) {
  int i = blockIdx.x*256 + threadIdx.x;
  if (i < n4) p[i] = float4{0.f, 0.f, 0.f, 0.f};
}

// ---------------- flags zeroing (per replay) ----------------
__global__ __launch_bounds__(256)
void zero_flags(int* __restrict__ f, int n) {
  int i = blockIdx.x*256 + threadIdx.x;
  if (i < n) f[i] = 0;
}

// ---------------- patch assignment + scan in one block ----------------
__global__ __launch_bounds__(1024)
void patch_scan(const float* __restrict__ node_table,
                const float* __restrict__ patch_emb,
                float* __restrict__ probs_st,
                float* __restrict__ nsoft,
                int* __restrict__ pk, int* __restrict__ cnt,
                int* __restrict__ offs) {
  __shared__ float pe[256];
  __shared__ int pid_s[NNODES];
  __shared__ int cnt_s[8], offs_s[8];
  int t = threadIdx.x;
  for (int k = t; k < 256; k += 1024) pe[k] = patch_emb[k];
  if (t < 8) cnt_s[t] = 0;
  __syncthreads();
  int am = -1;
  if (t < NNODES) {
    float nt[32];
#pragma unroll
    for (int j = 0; j < 32; ++j) nt[j] = node_table[t*32 + j];
    float lg[8];
#pragma unroll
    for (int r = 0; r < 8; ++r) {
      float a = 0.f;
#pragma unroll
      for (int j = 0; j < 32; ++j) a += nt[j] * pe[r*32 + j];
      lg[r] = a;
    }
    float m = lg[0];
#pragma unroll
    for (int r = 1; r < 8; ++r) m = fmaxf(m, lg[r]);
    float e[8]; float s = 0.f;
#pragma unroll
    for (int r = 0; r < 8; ++r) { e[r] = expf(lg[r] - m); s += e[r]; }
    float p[8];
#pragma unroll
    for (int r = 0; r < 8; ++r) p[r] = e[r] / s;
    am = 0; float best = p[0];
#pragma unroll
    for (int r = 1; r < 8; ++r) if (p[r] > best) { best = p[r]; am = r; }
    pid_s[t] = am;
    atomicAdd(&cnt_s[am], 1);
#pragma unroll
    for (int r = 0; r < 8; ++r) {
      float hard = (r == am) ? 1.f : 0.f;
      probs_st[t*8 + r] = (hard - p[r]) + p[r];
    }
#pragma unroll
    for (int j = 0; j < 32; ++j) {
      float a = 0.f;
#pragma unroll
      for (int r = 0; r < 8; ++r) a += p[r] * pe[r*32 + j];
      nsoft[t*32 + j] = a;
    }
  }
  __syncthreads();
  if (t == 0) {
    int o = 0;
#pragma unroll
    for (int r = 0; r < 8; ++r) {
      offs_s[r] = o; offs[r] = o; cnt[r] = cnt_s[r];
      o += (cnt_s[r] + 15) & ~15;
    }
  }
  __syncthreads();
  if (t < NNODES) {
    int pos = 0;
    for (int m = 0; m < t; ++m) pos += (pid_s[m] == am) ? 1 : 0;
    pk[t] = offs_s[am] + pos;
  }
}

// ---------------- embedding + fused LN0 -> pf (f32) and xn (bf16) ----------------
__global__ __launch_bounds__(160)
void embed_kernel(const float* __restrict__ x, const int* __restrict__ te,
                  const float* __restrict__ convW, const float* __restrict__ convB,
                  const float* __restrict__ tod, const float* __restrict__ dow,
                  const float* __restrict__ nsoft, const int* __restrict__ pk,
                  const float* __restrict__ g, const float* __restrict__ bt,
                  float* __restrict__ pf, unsigned short* __restrict__ xn) {
  int n = blockIdx.x, b = blockIdx.y, t = threadIdx.x;
  __shared__ float xs[3][12];
  __shared__ float rsum[160], rss[160];
  __shared__ float musv[2];
  if (t < 12) {
    int l = t;
    xs[0][l] = x[(b*12 + l)*NNODES + n];
    int base = ((b*12 + l)*NNODES + n)*2;
    xs[1][l] = (float)te[base]     / 288.0f;
    xs[2][l] = (float)te[base + 1] / 7.0f;
  }
  __syncthreads();
  int row = b*PBB + pk[n];
  float val;
  if (t < 64) {
    float a = convB[t];
#pragma unroll
    for (int c = 0; c < 3; ++c)
#pragma unroll
      for (int l = 0; l < 12; ++l)
        a += xs[c][l] * convW[t*36 + c*12 + l];
    val = a;
  } else if (t < 96) {
    int ti = te[((b*12 + 11)*NNODES + n)*2 + 0];
    val = tod[ti*32 + (t - 64)];
  } else if (t < 128) {
    int dw = te[((b*12 + 11)*NNODES + n)*2 + 1];
    val = dow[dw*32 + (t - 96)];
  } else {
    val = nsoft[n*32 + (t - 128)];
  }
  pf[row*DIMS_ + t] = val;
  rsum[t] = val; rss[t] = val*val;
  __syncthreads();
  if (t < 32) {
    float s = 0.f, ss = 0.f;
#pragma unroll
    for (int j = 0; j < 5; ++j) { s += rsum[t + 32*j]; ss += rss[t + 32*j]; }
    s  += __shfl_xor(s, 1, 32);  ss += __shfl_xor(ss, 1, 32);
    s  += __shfl_xor(s, 2, 32);  ss += __shfl_xor(ss, 2, 32);
    s  += __shfl_xor(s, 4, 32);  ss += __shfl_xor(ss, 4, 32);
    s  += __shfl_xor(s, 8, 32);  ss += __shfl_xor(ss, 8, 32);
    s  += __shfl_xor(s, 16, 32); ss += __shfl_xor(ss, 16, 32);
    if (t == 0) {
      float mu = s*(1.f/160.f);
      float var = ss*(1.f/160.f) - mu*mu;
      musv[0] = mu; musv[1] = rsqrtf(var + 1e-5f);
    }
  }
  __syncthreads();
  xn[(size_t)row*DIMS_ + t] = f2bf((val - musv[0])*musv[1]*g[t] + bt[t]);
}

// ---------------- all weight converts, 32x32 LDS tile transpose to bf16 [N][K] ----------------
__global__ __launch_bounds__(256)
void cvt_all(const float* __restrict__ attn_W, const float* __restrict__ mlp_W1,
             const float* __restrict__ mlp_W2,
             unsigned short* __restrict__ wt_attn, unsigned short* __restrict__ wt_w1,
             unsigned short* __restrict__ wt_w2) {
  int y = blockIdx.y;
  const float* src; unsigned short* dst; int K, N;
  if (y < 24)      { src = attn_W + (size_t)y*25600;        dst = wt_attn + (size_t)y*25600; K = 160; N = 160; }
  else if (y < 30) { int q = y-24; src = mlp_W1 + (size_t)q*160*320; dst = wt_w1 + (size_t)q*51200; K = 160; N = 320; }
  else             { int q = y-30; src = mlp_W2 + (size_t)q*320*160; dst = wt_w2 + (size_t)q*51200; K = 320; N = 160; }
  int tn = N >> 5, tk = K >> 5;
  int tile = blockIdx.x;
  if (tile >= tn*tk) return;
  int n0 = (tile % tn) << 5, k0 = (tile / tn) << 5;
  __shared__ unsigned short lds[32][33];
  int col = threadIdx.x & 31, rb = threadIdx.x >> 5;
#pragma unroll
  for (int rr = 0; rr < 4; ++rr) {
    int row = rb + 8*rr;
    lds[row][col] = f2bf(src[(size_t)(k0 + row)*N + n0 + col]);
  }
  __syncthreads();
#pragma unroll
  for (int rr = 0; rr < 4; ++rr) {
    int row = rb + 8*rr;
    dst[(size_t)(n0 + row)*K + k0 + col] = lds[col][row];
  }
}

// ---------------- QKV from swizzled L1 (30 tiles over 8 waves) ----------------
__device__ __forceinline__ void qkv_from_L1(const char* L1,
    const unsigned short* __restrict__ wq, const float* __restrict__ bq,
    unsigned short* __restrict__ qbN, bool transv,
    int row0, int wid, int r15, int kg) {
  constexpr size_t CY = (size_t)(RMAX2 + 16) * DIMS_;
  fx4 accq[4];
#pragma unroll
  for (int u = 0; u < 4; ++u) accq[u] = (fx4){0.f,0.f,0.f,0.f};
#pragma unroll
  for (int t = 0; t < 5; ++t) {
    short8v a4 = *(const short8v*)(const void*)(L1 + r15*384 + ((t*64 + kg*16) ^ ((r15 & 7) << 4)));
#pragma unroll
    for (int u = 0; u < 4; ++u) {
      int n = wid + 8*u;
      if (n < 30) {
        int z = n / 10, nn = n - z*10;
        short8v bfr = *(const short8v*)(const void*)
            (wq + (size_t)z*25600 + (size_t)(nn*16 + r15)*160 + t*32 + kg*8);
        accq[u] = __builtin_amdgcn_mfma_f32_16x16x32_bf16(a4, bfr, accq[u], 0, 0, 0);
      }
    }
  }
#pragma unroll
  for (int u = 0; u < 4; ++u) {
    int n = wid + 8*u;
    if (n >= 30) continue;
    int z = n / 10, nn = n - z*10;
    int col = nn*16 + r15;
    float bv = bq[z*160 + col];
    unsigned short* C = qbN + (size_t)z * CY;
#pragma unroll
    for (int i = 0; i < 4; ++i) {
      int rr = row0 + 4*kg + i;
      unsigned short h = f2bf(accq[u][i] + bv);
      if (transv && z == 2) C[(size_t)col*RMAXP + rr] = h;
      else                  C[(size_t)rr*DIMS_ + col] = h;
    }
  }
}

// ---------------- persistent cooperative kernel: QKV0 + 6 fused layers ----------------
// Dataflow sync: per-block flags instead of grid.sync. flags[wb*GXNUM + blk] = 1 when
// block blk's QKV for layer wb is visible. Trunk stays in registers across layers.
__global__ __launch_bounds__(512, 4)
void layers_coop(unsigned short* __restrict__ qbA, unsigned short* __restrict__ qbB,
                 const unsigned short* __restrict__ wt_attn,
                 const unsigned short* __restrict__ wt_w1,
                 const unsigned short* __restrict__ wt_w2,
                 const float* __restrict__ attn_b, const float* __restrict__ mlp_b1,
                 const float* __restrict__ mlp_b2,
                 const float* __restrict__ ln_scale, const float* __restrict__ ln_bias,
                 const unsigned short* __restrict__ xn, float* __restrict__ pf,
                 const int* __restrict__ cnt, const int* __restrict__ offs,
                 int* __restrict__ flags) {
  constexpr size_t CY = (size_t)(RMAX2 + 16) * DIMS_;
  __shared__ unsigned short L1s[16*192];
  __shared__ unsigned short L2s[16*320];
  __shared__ float sA[8][16], ssA[8][16];
  __shared__ float Sf[16*256];
  __shared__ unsigned short Pl[16*256];
  __shared__ float Sinv[16];
  __shared__ int cs[8], os[8];
  char* L1 = (char*)L1s; char* L2 = (char*)L2s; char* Pb = (char*)Pl;
  const float scale = 0.07905694150420949f;

  int tid = threadIdx.x;
  int wid = tid >> 6;
  int lane = tid & 63;
  int r15 = lane & 15, kg = lane >> 4;
  int row0 = blockIdx.x * 16;
  if (tid < 8) { cs[tid] = cnt[tid]; os[tid] = offs[tid]; }
  __syncthreads();
  int b = row0 / PBB;
  int local = row0 - b*PBB;
  int r = 7;
#pragma unroll
  for (int rr = 6; rr >= 0; --rr) if (local < os[rr+1]) r = rr;
  int L = cs[r];
  int q0 = local - os[r];
  int bo = b*PBB + os[r];
  int ntP = (wid < 2) ? 2 : 1;
  int ntM = (wid < 4) ? 3 : 2;

  // ---- trunk registers
  float trunk[2][4];
#pragma unroll
  for (int u = 0; u < 2; ++u)
    if (u < ntP) {
      int col = (wid + 8*u)*16 + r15;
#pragma unroll
      for (int i = 0; i < 4; ++i)
        trunk[u][i] = pf[(size_t)(row0 + 4*kg + i)*DIMS_ + col];
    }

  // ---- pre-phase: QKV0 from xn, V transposed (layer 0 intra)
  for (int k = tid; k < 16*DIMS_; k += 512) {
    int row = k / DIMS_, col = k - row*DIMS_;
    int byte = row*384 + ((col*2) ^ ((row & 7) << 4));
    *(unsigned short*)(L1 + byte) = xn[(size_t)(row0 + row)*DIMS_ + col];
  }
  __syncthreads();
  qkv_from_L1(L1, wt_attn, attn_b, qbA, true, row0, wid, r15, kg);
  __threadfence();
  __syncthreads();
  if (tid == 0)
    __hip_atomic_store(&flags[0*GXNUM + (int)blockIdx.x], 1, __ATOMIC_RELEASE, __HIP_MEMORY_SCOPE_AGENT);

  for (int wb = 0; wb < 6; ++wb) {
    bool intra = ((wb & 1) == 0);
    bool hasnext = (wb < 5);
    unsigned short* qbCur = (wb & 1) ? qbB : qbA;
    unsigned short* qbNext = (wb & 1) ? qbA : qbB;
    const unsigned short* qb = qbCur;
    const unsigned short* kb = qbCur + CY;
    const unsigned short* vt = qbCur + 2*CY;
    const unsigned short* wqkv = wt_attn + (size_t)wb*4*25600;
    const float* bbase = attn_b + (size_t)wb*4*DIMS_;
    const unsigned short* wproj = wqkv + 3*25600;
    const float* bproj = bbase + 3*DIMS_;
    const unsigned short* w1 = wt_w1 + (size_t)wb*51200;
    const unsigned short* w2 = wt_w2 + (size_t)wb*51200;
    const float* b1v = mlp_b1 + (size_t)wb*HID_;
    const float* b2v = mlp_b2 + (size_t)wb*DIMS_;
    const float* g1  = ln_scale + (size_t)(2*wb + 1)*DIMS_;
    const float* bt1 = ln_bias  + (size_t)(2*wb + 1)*DIMS_;
    const float* gn  = ln_scale + (size_t)(2*wb + 2)*DIMS_;
    const float* btn = ln_bias  + (size_t)(2*wb + 2)*DIMS_;
    const unsigned short* wqkvN = wt_attn + (size_t)(wb+1)*4*25600;
    const float* bqkvN = attn_b + (size_t)(wb+1)*4*DIMS_;

    // ---- dataflow wait: QKV deps of layer wb
    {
      const int fbase = wb*GXNUM;
      if (intra) {
        int nkt = (L + 15) >> 4;
        int blk0 = bo >> 4;
        if (tid < nkt) {
          while (__hip_atomic_load(&flags[fbase + blk0 + tid], __ATOMIC_RELAXED, __HIP_MEMORY_SCOPE_AGENT) == 0) {}
        }
      } else {
        if (tid < 8 && q0 < cs[tid]) {
          int dep = (b*PBB + os[tid] + q0) >> 4;
          while (__hip_atomic_load(&flags[fbase + dep], __ATOMIC_RELAXED, __HIP_MEMORY_SCOPE_AGENT) == 0) {}
        }
      }
      __syncthreads();
      __threadfence();
    }

    // =================== attention -> ab in L1 ===================
    if (intra) {
      int nkt = (L + 15) >> 4;
      int npv = (L + 31) >> 5;
      short8v qf[5];
      {
        const unsigned short* Qr = qb + (size_t)(row0 + r15)*DIMS_ + kg*8;
#pragma unroll
        for (int kk = 0; kk < 5; ++kk) qf[kk] = *(const short8v*)(const void*)(Qr + kk*32);
      }
#pragma unroll
      for (int u = 0; u < 2; ++u) {
        int t = wid + 8*u;
        if (t < nkt) {
          fx4 a = (fx4){0.f,0.f,0.f,0.f};
          const unsigned short* Kr = kb + (size_t)(bo + t*16 + r15)*DIMS_ + kg*8;
#pragma unroll
          for (int kk = 0; kk < 5; ++kk) {
            short8v kf = *(const short8v*)(const void*)(Kr + kk*32);
            a = __builtin_amdgcn_mfma_f32_16x16x32_bf16(qf[kk], kf, a, 0, 0, 0);
          }
          int j = t*16 + r15;
#pragma unroll
          for (int i = 0; i < 4; ++i)
            Sf[(4*kg + i)*256 + j] = (j < L) ? a[i]*scale : -1e30f;
        }
      }
      __syncthreads();
      {
        int qq = lane >> 5, l32 = lane & 31;
        int row = 2*wid + qq;
        float vals[8];
        float mx = -1e30f;
#pragma unroll
        for (int k = 0; k < 8; ++k) {
          int j = l32 + 32*k;
          float v = (j < L) ? Sf[row*256 + j] : -1e30f;
          vals[k] = v; mx = fmaxf(mx, v);
        }
        mx = fmaxf(mx, __shfl_xor(mx, 1, 32));
        mx = fmaxf(mx, __shfl_xor(mx, 2, 32));
        mx = fmaxf(mx, __shfl_xor(mx, 4, 32));
        mx = fmaxf(mx, __shfl_xor(mx, 8, 32));
        mx = fmaxf(mx, __shfl_xor(mx, 16, 32));
        float sum = 0.f;
#pragma unroll
        for (int k = 0; k < 8; ++k) {
          float e = (vals[k] > -1e29f) ? expf(vals[k] - mx) : 0.f;
          vals[k] = e; sum += e;
        }
        sum += __shfl_xor(sum, 1, 32);
        sum += __shfl_xor(sum, 2, 32);
        sum += __shfl_xor(sum, 4, 32);
        sum += __shfl_xor(sum, 8, 32);
        sum += __shfl_xor(sum, 16, 32);
        if (l32 == 0) Sinv[row] = (sum > 0.f) ? 1.f/sum : 0.f;
#pragma unroll
        for (int k = 0; k < 8; ++k) {
          int j = l32 + 32*k;
          int byte = row*512 + ((j*2) ^ ((row & 7) << 4));
          *(unsigned short*)(Pb + byte) = f2bf(vals[k]);
        }
      }
      __syncthreads();
      fx4 o[2];
#pragma unroll
      for (int u = 0; u < 2; ++u) o[u] = (fx4){0.f,0.f,0.f,0.f};
#pragma unroll
      for (int sS = 0; sS < 8; ++sS) {
        if (sS < npv) {
          short8v pfr = *(const short8v*)(const void*)
              (Pb + r15*512 + ((sS*64 + kg*16) ^ ((r15 & 7) << 4)));
#pragma unroll
          for (int u = 0; u < 2; ++u)
            if (u < ntP) {
              int n = wid + 8*u;
              const unsigned short* Vr = vt + (size_t)(n*16 + r15)*RMAXP + bo + sS*32 + kg*8;
              short8v vf = *(const short8v*)(const void*)Vr;
              o[u] = __builtin_amdgcn_mfma_f32_16x16x32_bf16(pfr, vf, o[u], 0, 0, 0);
            }
        }
      }
      float inv[4];
#pragma unroll
      for (int i = 0; i < 4; ++i) inv[i] = Sinv[4*kg + i];
#pragma unroll
      for (int u = 0; u < 2; ++u)
        if (u < ntP) {
          int n = wid + 8*u;
#pragma unroll
          for (int i = 0; i < 4; ++i) {
            int row = 4*kg + i, d = n*16 + r15;
            int byte = row*384 + ((d*2) ^ ((row & 7) << 4));
            *(unsigned short*)(L1 + byte) = f2bf(o[u][i]*inv[i]);
          }
        }
    } else {
      int qq = lane >> 5, l32 = lane & 31;
      int rowT = 2*wid + qq;
      int p = q0 + rowT;
      bool vq = p < L;
      int j = l32 >> 2, c = l32 & 3;
      int cj = cs[j];
      bool vk = p < cj;
      int keyrow = b*PBB + os[j] + (vk ? p : 0);
      int qrow = row0 + rowT;
      float part = 0.f;
      {
        const unsigned short* qr = qb + (size_t)qrow*DIMS_ + c*40;
        const unsigned short* kr = kb + (size_t)keyrow*DIMS_ + c*40;
#pragma unroll
        for (int dd = 0; dd < 5; ++dd) {
          short8v a8 = *(const short8v*)(const void*)(qr + dd*8);
          short8v b8 = *(const short8v*)(const void*)(kr + dd*8);
#pragma unroll
          for (int u = 0; u < 8; ++u)
            part += bf2f((unsigned short)a8[u]) * bf2f((unsigned short)b8[u]);
        }
      }
      part += __shfl_xor(part, 1, 4);
      part += __shfl_xor(part, 2, 4);
      float sc = (vq && vk) ? part*scale : -1e30f;
      float m = sc;
      m = fmaxf(m, __shfl_xor(m, 4, 32));
      m = fmaxf(m, __shfl_xor(m, 8, 32));
      m = fmaxf(m, __shfl_xor(m, 16, 32));
      float e = (vq && vk) ? expf(sc - m) : 0.f;
      float sum = e;
      sum += __shfl_xor(sum, 4, 32);
      sum += __shfl_xor(sum, 8, 32);
      sum += __shfl_xor(sum, 16, 32);
      float w = (vq && vk && sum > 0.f) ? e/sum : 0.f;
      float o[5];
#pragma unroll
      for (int k = 0; k < 5; ++k) o[k] = 0.f;
      int qbase = qq*32;
#pragma unroll
      for (int jj = 0; jj < 8; ++jj) {
        float wv = __shfl(w, qbase + jj*4);
        int kr2 = __shfl(keyrow, qbase + jj*4);
        if (wv > 0.f) {
          const unsigned short* Vr = vt + (size_t)kr2*DIMS_;
#pragma unroll
          for (int k = 0; k < 5; ++k) o[k] += wv * bf2f(Vr[l32 + 32*k]);
        }
      }
#pragma unroll
      for (int k = 0; k < 5; ++k) {
        int d = l32 + 32*k;
        int byte = rowT*384 + ((d*2) ^ ((rowT & 7) << 4));
        *(unsigned short*)(L1 + byte) = f2bf(vq ? o[k] : 0.f);
      }
    }
    __syncthreads();

    // =================== phase 1: proj (trunk in registers) ===================
    short8v af[5];
#pragma unroll
    for (int t = 0; t < 5; ++t)
      af[t] = *(const short8v*)(const void*)(L1 + r15*384 + ((t*64 + kg*16) ^ ((r15 & 7) << 4)));
    fx4 acc[2];
#pragma unroll
    for (int u = 0; u < 2; ++u) acc[u] = (fx4){0.f,0.f,0.f,0.f};
#pragma unroll
    for (int t = 0; t < 5; ++t)
#pragma unroll
      for (int u = 0; u < 2; ++u)
        if (u < ntP) {
          int n = wid + 8*u;
          short8v bfr = *(const short8v*)(const void*)(wproj + (size_t)(n*16 + r15)*160 + t*32 + kg*8);
          acc[u] = __builtin_amdgcn_mfma_f32_16x16x32_bf16(af[t], bfr, acc[u], 0, 0, 0);
        }

    float sv[4] = {0,0,0,0}, ssv[4] = {0,0,0,0};
#pragma unroll
    for (int u = 0; u < 2; ++u)
      if (u < ntP) {
        int n = wid + 8*u;
        int col = n*16 + r15;
        float bv = bproj[col];
#pragma unroll
        for (int i = 0; i < 4; ++i) {
          float v = trunk[u][i] + acc[u][i] + bv;
          trunk[u][i] = v;
          sv[i] += v; ssv[i] += v*v;
        }
      }
#pragma unroll
    for (int i = 0; i < 4; ++i) {
      sv[i] += __shfl_xor(sv[i], 1, 16); ssv[i] += __shfl_xor(ssv[i], 1, 16);
      sv[i] += __shfl_xor(sv[i], 2, 16); ssv[i] += __shfl_xor(ssv[i], 2, 16);
      sv[i] += __shfl_xor(sv[i], 4, 16); ssv[i] += __shfl_xor(ssv[i], 4, 16);
      sv[i] += __shfl_xor(sv[i], 8, 16); ssv[i] += __shfl_xor(ssv[i], 8, 16);
    }
    if (r15 == 0) {
#pragma unroll
      for (int i = 0; i < 4; ++i) { sA[wid][4*kg+i] = sv[i]; ssA[wid][4*kg+i] = ssv[i]; }
    }
    __syncthreads();
    float mu[4], rs[4];
#pragma unroll
    for (int i = 0; i < 4; ++i) {
      float st = 0.f, sst = 0.f;
#pragma unroll
      for (int w = 0; w < 8; ++w) { st += sA[w][4*kg+i]; sst += ssA[w][4*kg+i]; }
      mu[i] = st*(1.f/160.f);
      float var = sst*(1.f/160.f) - mu[i]*mu[i];
      rs[i] = rsqrtf(var + 1e-5f);
    }
#pragma unroll
    for (int u = 0; u < 2; ++u)
      if (u < ntP) {
        int n = wid + 8*u;
        int col = n*16 + r15;
        float gv = g1[col], bv = bt1[col];
#pragma unroll
        for (int i = 0; i < 4; ++i) {
          int row = 4*kg + i;
          int byte = row*384 + ((col*2) ^ ((row & 7) << 4));
          *(unsigned short*)(L1 + byte) = f2bf((trunk[u][i] - mu[i])*rs[i]*gv + bv);
        }
      }
    __syncthreads();

    // =================== phase 2: MLP1 + gelu -> L2 ===================
    fx4 acc2[3];
#pragma unroll
    for (int u = 0; u < 3; ++u) acc2[u] = (fx4){0.f,0.f,0.f,0.f};
#pragma unroll
    for (int t = 0; t < 5; ++t) {
      short8v a2 = *(const short8v*)(const void*)(L1 + r15*384 + ((t*64 + kg*16) ^ ((r15 & 7) << 4)));
#pragma unroll
      for (int u = 0; u < 3; ++u)
        if (u < ntM) {
          int n = wid + 8*u;
          short8v bfr = *(const short8v*)(const void*)(w1 + (size_t)(n*16 + r15)*160 + t*32 + kg*8);
          acc2[u] = __builtin_amdgcn_mfma_f32_16x16x32_bf16(a2, bfr, acc2[u], 0, 0, 0);
        }
    }
#pragma unroll
    for (int u = 0; u < 3; ++u)
      if (u < ntM) {
        int n = wid + 8*u;
        int col = n*16 + r15;
        float bv = b1v[col];
#pragma unroll
        for (int i = 0; i < 4; ++i) {
          float v = gelu_f(acc2[u][i] + bv);
          int row = 4*kg + i;
          int byte = row*640 + ((col*2) ^ ((row & 7) << 4));
          *(unsigned short*)(L2 + byte) = f2bf(v);
        }
      }
    __syncthreads();

    // =================== phase 3: MLP2 + residual (trunk) ===================
    fx4 acc3[2];
#pragma unroll
    for (int u = 0; u < 2; ++u) acc3[u] = (fx4){0.f,0.f,0.f,0.f};
#pragma unroll
    for (int t = 0; t < 10; ++t) {
      short8v a3 = *(const short8v*)(const void*)(L2 + r15*640 + ((t*64 + kg*16) ^ ((r15 & 7) << 4)));
#pragma unroll
      for (int u = 0; u < 2; ++u)
        if (u < ntP) {
          int n = wid + 8*u;
          short8v bfr = *(const short8v*)(const void*)(w2 + (size_t)(n*16 + r15)*320 + t*32 + kg*8);
          acc3[u] = __builtin_amdgcn_mfma_f32_16x16x32_bf16(a3, bfr, acc3[u], 0, 0, 0);
        }
    }
    float sv2[4] = {0,0,0,0}, ssv2[4] = {0,0,0,0};
#pragma unroll
    for (int u = 0; u < 2; ++u)
      if (u < ntP) {
        int n = wid + 8*u;
        int col = n*16 + r15;
        float bv = b2v[col];
#pragma unroll
        for (int i = 0; i < 4; ++i) {
          float v = trunk[u][i] + acc3[u][i] + bv;
          trunk[u][i] = v;
          sv2[i] += v; ssv2[i] += v*v;
        }
      }

    if (hasnext) {
      // =================== phase 4: LN_next -> L1 ===================
#pragma unroll
      for (int i = 0; i < 4; ++i) {
        sv2[i] += __shfl_xor(sv2[i], 1, 16); ssv2[i] += __shfl_xor(ssv2[i], 1, 16);
        sv2[i] += __shfl_xor(sv2[i], 2, 16); ssv2[i] += __shfl_xor(ssv2[i], 2, 16);
        sv2[i] += __shfl_xor(sv2[i], 4, 16); ssv2[i] += __shfl_xor(ssv2[i], 4, 16);
        sv2[i] += __shfl_xor(sv2[i], 8, 16); ssv2[i] += __shfl_xor(ssv2[i], 8, 16);
      }
      __syncthreads();
      if (r15 == 0) {
#pragma unroll
        for (int i = 0; i < 4; ++i) { sA[wid][4*kg+i] = sv2[i]; ssA[wid][4*kg+i] = ssv2[i]; }
      }
      __syncthreads();
#pragma unroll
      for (int i = 0; i < 4; ++i) {
        float st = 0.f, sst = 0.f;
#pragma unroll
        for (int w = 0; w < 8; ++w) { st += sA[w][4*kg+i]; sst += ssA[w][4*kg+i]; }
        mu[i] = st*(1.f/160.f);
        float var = sst*(1.f/160.f) - mu[i]*mu[i];
        rs[i] = rsqrtf(var + 1e-5f);
      }
#pragma unroll
      for (int u = 0; u < 2; ++u)
        if (u < ntP) {
          int n = wid + 8*u;
          int col = n*16 + r15;
          float gv = gn[col], bv = btn[col];
#pragma unroll
          for (int i = 0; i < 4; ++i) {
            int row = 4*kg + i;
            int byte = row*384 + ((col*2) ^ ((row & 7) << 4));
            *(unsigned short*)(L1 + byte) = f2bf((trunk[u][i] - mu[i])*rs[i]*gv + bv);
          }
        }
      __syncthreads();

      // =================== phase 5: QKV_next + flag ===================
      qkv_from_L1(L1, wqkvN, bqkvN, qbNext, (wb & 1) != 0, row0, wid, r15, kg);
      __threadfence();
      __syncthreads();
      if (tid == 0)
        __hip_atomic_store(&flags[(wb+1)*GXNUM + (int)blockIdx.x], 1, __ATOMIC_RELEASE, __HIP_MEMORY_SCOPE_AGENT);
    }
  }

  // final: write trunk to pf once
#pragma unroll
  for (int u = 0; u < 2; ++u)
    if (u < ntP) {
      int col = (wid + 8*u)*16 + r15;
#pragma unroll
      for (int i = 0; i < 4; ++i)
        pf[(size_t)(row0 + 4*kg + i)*DIMS_ + col] = trunk[u][i];
    }
}

// ---------------- fallback: per-layer kernel ----------------
template<bool INTRA, bool HASNEXT, bool TRANSV_NEXT>
__global__ __launch_bounds__(512)
void fused_layer(const unsigned short* __restrict__ qb,
                 const unsigned short* __restrict__ kb,
                 const unsigned short* __restrict__ vt,
                 const unsigned short* __restrict__ wproj, const float* __restrict__ bproj,
                 const unsigned short* __restrict__ w1, const float* __restrict__ b1v,
                 const unsigned short* __restrict__ w2, const float* __restrict__ b2v,
                 const float* __restrict__ g1, const float* __restrict__ bt1,
                 const float* __restrict__ gn, const float* __restrict__ btn,
                 const unsigned short* __restrict__ wqkvN, const float* __restrict__ bqkvN,
                 float* __restrict__ pf, unsigned short* __restrict__ qbN,
                 const int* __restrict__ cnt, const int* __restrict__ offs) {
  __shared__ unsigned short L1s[16*192];
  __shared__ unsigned short L2s[16*320];
  __shared__ float sA[8][16], ssA[8][16];
  __shared__ float Sf[INTRA ? 16*256 : 1];
  __shared__ unsigned short Pl[INTRA ? 16*256 : 1];
  __shared__ float Sinv[16];
  __shared__ int cs[8], os[8];
  char* L1 = (char*)L1s; char* L2 = (char*)L2s; char* Pb = (char*)Pl;
  const float scale = 0.07905694150420949f;

  int tid = threadIdx.x;
  int wid = tid >> 6;
  int lane = tid & 63;
  int r15 = lane & 15, kg = lane >> 4;
  int row0 = blockIdx.x * 16;
  if (tid < 8) { cs[tid] = cnt[tid]; os[tid] = offs[tid]; }
  __syncthreads();
  int b = row0 / PBB;
  int local = row0 - b*PBB;
  int r = 7;
#pragma unroll
  for (int rr = 6; rr >= 0; --rr) if (local < os[rr+1]) r = rr;
  int L = cs[r];
  int q0 = local - os[r];
  int bo = b*PBB + os[r];
  int ntP = (wid < 2) ? 2 : 1;
  int ntM = (wid < 4) ? 3 : 2;

  if (INTRA) {
    int nkt = (L + 15) >> 4;
    int npv = (L + 31) >> 5;
    short8v qf[5];
    {
      const unsigned short* Qr = qb + (size_t)(row0 + r15)*DIMS_ + kg*8;
#pragma unroll
      for (int kk = 0; kk < 5; ++kk) qf[kk] = *(const short8v*)(const void*)(Qr + kk*32);
    }
#pragma unroll
    for (int u = 0; u < 2; ++u) {
      int t = wid + 8*u;
      if (t < nkt) {
        fx4 a = (fx4){0.f,0.f,0.f,0.f};
        const unsigned short* Kr = kb + (size_t)(bo + t*16 + r15)*DIMS_ + kg*8;
#pragma unroll
        for (int kk = 0; kk < 5; ++kk) {
          short8v kf = *(const short8v*)(const void*)(Kr + kk*32);
          a = __builtin_amdgcn_mfma_f32_16x16x32_bf16(qf[kk], kf, a, 0, 0, 0);
        }
        int j = t*16 + r15;
#pragma unroll
        for (int i = 0; i < 4; ++i)
          Sf[(4*kg + i)*256 + j] = (j < L) ? a[i]*scale : -1e30f;
      }
    }
    __syncthreads();
    {
      int qq = lane >> 5, l32 = lane & 31;
      int row = 2*wid + qq;
      float vals[8];
      float mx = -1e30f;
#pragma unroll
      for (int k = 0; k < 8; ++k) {
        int j = l32 + 32*k;
        float v = (j < L) ? Sf[row*256 + j] : -1e30f;
        vals[k] = v; mx = fmaxf(mx, v);
      }
      mx = fmaxf(mx, __shfl_xor(mx, 1, 32));
      mx = fmaxf(mx, __shfl_xor(mx, 2, 32));
      mx = fmaxf(mx, __shfl_xor(mx, 4, 32));
      mx = fmaxf(mx, __shfl_xor(mx, 8, 32));
      mx = fmaxf(mx, __shfl_xor(mx, 16, 32));
      float sum = 0.f;
#pragma unroll
      for (int k = 0; k < 8; ++k) {
        float e = (vals[k] > -1e29f) ? expf(vals[k] - mx) : 0.f;
        vals[k] = e; sum += e;
      }
      sum += __shfl_xor(sum, 1, 32);
      sum += __shfl_xor(sum, 2, 32);
      sum += __shfl_xor(sum, 4, 32);
      sum += __shfl_xor(sum, 8, 32);
      sum += __shfl_xor(sum, 16, 32);
      if (l32 == 0) Sinv[row] = (sum > 0.f) ? 1.f/sum : 0.f;
#pragma unroll
      for (int k = 0; k < 8; ++k) {
        int j = l32 + 32*k;
        int byte = row*512 + ((j*2) ^ ((row & 7) << 4));
        *(unsigned short*)(Pb + byte) = f2bf(vals[k]);
      }
    }
    __syncthreads();
    fx4 o[2];
#pragma unroll
    for (int u = 0; u < 2; ++u) o[u] = (fx4){0.f,0.f,0.f,0.f};
#pragma unroll
    for (int sS = 0; sS < 8; ++sS) {
      if (sS < npv) {
        short8v pfr = *(const short8v*)(const void*)
            (Pb + r15*512 + ((sS*64 + kg*16) ^ ((r15 & 7) << 4)));
#pragma unroll
        for (int u = 0; u < 2; ++u)
          if (u < ntP) {
            int n = wid + 8*u;
            const unsigned short* Vr = vt + (size_t)(n*16 + r15)*RMAXP + bo + sS*32 + kg*8;
            short8v vf = *(const short8v*)(const void*)Vr;
            o[u] = __builtin_amdgcn_mfma_f32_16x16x32_bf16(pfr, vf, o[u], 0, 0, 0);
          }
      }
    }
    float inv[4];
#pragma unroll
    for (int i = 0; i < 4; ++i) inv[i] = Sinv[4*kg + i];
#pragma unroll
    for (int u = 0; u < 2; ++u)
      if (u < ntP) {
        int n = wid + 8*u;
#pragma unroll
        for (int i = 0; i < 4; ++i) {
          int row = 4*kg + i, d = n*16 + r15;
          int byte = row*384 + ((d*2) ^ ((row & 7) << 4));
          *(unsigned short*)(L1 + byte) = f2bf(o[u][i]*inv[i]);
        }
      }
  } else {
    int qq = lane >> 5, l32 = lane & 31;
    int rowT = 2*wid + qq;
    int p = q0 + rowT;
    bool vq = p < L;
    int j = l32 >> 2, c = l32 & 3;
    int cj = cs[j];
    bool vk = p < cj;
    int keyrow = b*PBB + os[j] + (vk ? p : 0);
    int qrow = row0 + rowT;
    float part = 0.f;
    {
      const unsigned short* qr = qb + (size_t)qrow*DIMS_ + c*40;
      const unsigned short* kr = kb + (size_t)keyrow*DIMS_ + c*40;
#pragma unroll
      for (int dd = 0; dd < 5; ++dd) {
        short8v a8 = *(const short8v*)(const void*)(qr + dd*8);
        short8v b8 = *(const short8v*)(const void*)(kr + dd*8);
#pragma unroll
        for (int u = 0; u < 8; ++u)
          part += bf2f((unsigned short)a8[u]) * bf2f((unsigned short)b8[u]);
      }
    }
    part += __shfl_xor(part, 1, 4);
    part += __shfl_xor(part, 2, 4);
    float sc = (vq && vk) ? part*scale : -1e30f;
    float m = sc;
    m = fmaxf(m, __shfl_xor(m, 4, 32));
    m = fmaxf(m, __shfl_xor(m, 8, 32));
    m = fmaxf(m, __shfl_xor(m, 16, 32));
    float e = (vq && vk) ? expf(sc - m) : 0.f;
    float sum = e;
    sum += __shfl_xor(sum, 4, 32);
    sum += __shfl_xor(sum, 8, 32);
    sum += __shfl_xor(sum, 16, 32);
    float w = (vq && vk && sum > 0.f) ? e/sum : 0.f;
    float o[5];
#pragma unroll
    for (int k = 0; k < 5; ++k) o[k] = 0.f;
    int qbase = qq*32;
#pragma unroll
    for (int jj = 0; jj < 8; ++jj) {
      float wv = __shfl(w, qbase + jj*4);
      int kr2 = __shfl(keyrow, qbase + jj*4);
      if (wv > 0.f) {
        const unsigned short* Vr = vt + (size_t)kr2*DIMS_;
#pragma unroll
        for (int k = 0; k < 5; ++k) o[k] += wv * bf2f(Vr[l32 + 32*k]);
      }
    }
#pragma unroll
    for (int k = 0; k < 5; ++k) {
      int d = l32 + 32*k;
      int byte = rowT*384 + ((d*2) ^ ((rowT & 7) << 4));
      *(unsigned short*)(L1 + byte) = f2bf(vq ? o[k] : 0.f);
    }
  }
  __syncthreads();

  short8v af[5];
#pragma unroll
  for (int t = 0; t < 5; ++t)
    af[t] = *(const short8v*)(const void*)(L1 + r15*384 + ((t*64 + kg*16) ^ ((r15 & 7) << 4)));
  fx4 acc[2];
#pragma unroll
  for (int u = 0; u < 2; ++u) acc[u] = (fx4){0.f,0.f,0.f,0.f};
#pragma unroll
  for (int t = 0; t < 5; ++t)
#pragma unroll
    for (int u = 0; u < 2; ++u)
      if (u < ntP) {
        int n = wid + 8*u;
        short8v bfr = *(const short8v*)(const void*)(wproj + (size_t)(n*16 + r15)*160 + t*32 + kg*8);
        acc[u] = __builtin_amdgcn_mfma_f32_16x16x32_bf16(af[t], bfr, acc[u], 0, 0, 0);
      }

  float pn[2][4];
  float sv[4] = {0,0,0,0}, ssv[4] = {0,0,0,0};
#pragma unroll
  for (int u = 0; u < 2; ++u)
    if (u < ntP) {
      int n = wid + 8*u;
      int col = n*16 + r15;
      float bv = bproj[col];
#pragma unroll
      for (int i = 0; i < 4; ++i) {
        int row = row0 + 4*kg + i;
        float v = pf[(size_t)row*DIMS_ + col] + acc[u][i] + bv;
        pn[u][i] = v;
        pf[(size_t)row*DIMS_ + col] = v;
        sv[i] += v; ssv[i] += v*v;
      }
    }
#pragma unroll
  for (int i = 0; i < 4; ++i) {
    sv[i] += __shfl_xor(sv[i], 1, 16); ssv[i] += __shfl_xor(ssv[i], 1, 16);
    sv[i] += __shfl_xor(sv[i], 2, 16); ssv[i] += __shfl_xor(ssv[i], 2, 16);
    sv[i] += __shfl_xor(sv[i], 4, 16); ssv[i] += __shfl_xor(ssv[i], 4, 16);
    sv[i] += __shfl_xor(sv[i], 8, 16); ssv[i] += __shfl_xor(ssv[i], 8, 16);
  }
  if (r15 == 0) {
#pragma unroll
    for (int i = 0; i < 4; ++i) { sA[wid][4*kg+i] = sv[i]; ssA[wid][4*kg+i] = ssv[i]; }
  }
  __syncthreads();
  float mu[4], rs[4];
#pragma unroll
  for (int i = 0; i < 4; ++i) {
    float st = 0.f, sst = 0.f;
#pragma unroll
    for (int w = 0; w < 8; ++w) { st += sA[w][4*kg+i]; sst += ssA[w][4*kg+i]; }
    mu[i] = st*(1.f/160.f);
    float var = sst*(1.f/160.f) - mu[i]*mu[i];
    rs[i] = rsqrtf(var + 1e-5f);
  }
#pragma unroll
  for (int u = 0; u < 2; ++u)
    if (u < ntP) {
      int n = wid + 8*u;
      int col = n*16 + r15;
      float gv = g1[col], bv = bt1[col];
#pragma unroll
      for (int i = 0; i < 4; ++i) {
        int row = 4*kg + i;
        int byte = row*384 + ((col*2) ^ ((row & 7) << 4));
        *(unsigned short*)(L1 + byte) = f2bf((pn[u][i] - mu[i])*rs[i]*gv + bv);
      }
    }
  __syncthreads();

  fx4 acc2[3];
#pragma unroll
  for (int u = 0; u < 3; ++u) acc2[u] = (fx4){0.f,0.f,0.f,0.f};
#pragma unroll
  for (int t = 0; t < 5; ++t) {
    short8v a2 = *(const short8v*)(const void*)(L1 + r15*384 + ((t*64 + kg*16) ^ ((r15 & 7) << 4)));
#pragma unroll
    for (int u = 0; u < 3; ++u)
      if (u < ntM) {
        int n = wid + 8*u;
        short8v bfr = *(const short8v*)(const void*)(w1 + (size_t)(n*16 + r15)*160 + t*32 + kg*8);
        acc2[u] = __builtin_amdgcn_mfma_f32_16x16x32_bf16(a2, bfr, acc2[u], 0, 0, 0);
      }
  }
#pragma unroll
  for (int u = 0; u < 3; ++u)
    if (u < ntM) {
      int n = wid + 8*u;
      int col = n*16 + r15;
      float bv = b1v[col];
#pragma unroll
      for (int i = 0; i < 4; ++i) {
        float v = gelu_f(acc2[u][i] + bv);
        int row = 4*kg + i;
        int byte = row*640 + ((col*2) ^ ((row & 7) << 4));
        *(unsigned short*)(L2 + byte) = f2bf(v);
      }
    }
  __syncthreads();

  fx4 acc3[2];
#pragma unroll
  for (int u = 0; u < 2; ++u) acc3[u] = (fx4){0.f,0.f,0.f,0.f};
#pragma unroll
  for (int t = 0; t < 10; ++t) {
    short8v a3 = *(const short8v*)(const void*)(L2 + r15*640 + ((t*64 + kg*16) ^ ((r15 & 7) << 4)));
#pragma unroll
    for (int u = 0; u < 2; ++u)
      if (u < ntP) {
        int n = wid + 8*u;
        short8v bfr = *(const short8v*)(const void*)(w2 + (size_t)(n*16 + r15)*320 + t*32 + kg*8);
        acc3[u] = __builtin_amdgcn_mfma_f32_16x16x32_bf16(a3, bfr, acc3[u], 0, 0, 0);
      }
  }
  float sv2[4] = {0,0,0,0}, ssv2[4] = {0,0,0,0};
  float fnv[2][4];
#pragma unroll
  for (int u = 0; u < 2; ++u)
    if (u < ntP) {
      int n = wid + 8*u;
      int col = n*16 + r15;
      float bv = b2v[col];
#pragma unroll
      for (int i = 0; i < 4; ++i) {
        float v = pn[u][i] + acc3[u][i] + bv;
        fnv[u][i] = v;
        pf[(size_t)(row0 + 4*kg + i)*DIMS_ + col] = v;
        sv2[i] += v; ssv2[i] += v*v;
      }
    }
  if (!HASNEXT) return;

#pragma unroll
  for (int i = 0; i < 4; ++i) {
    sv2[i] += __shfl_xor(sv2[i], 1, 16); ssv2[i] += __shfl_xor(ssv2[i], 1, 16);
    sv2[i] += __shfl_xor(sv2[i], 2, 16); ssv2[i] += __shfl_xor(ssv2[i], 2, 16);
    sv2[i] += __shfl_xor(sv2[i], 4, 16); ssv2[i] += __shfl_xor(ssv2[i], 4, 16);
    sv2[i] += __shfl_xor(sv2[i], 8, 16); ssv2[i] += __shfl_xor(ssv2[i], 8, 16);
  }
  __syncthreads();
  if (r15 == 0) {
#pragma unroll
    for (int i = 0; i < 4; ++i) { sA[wid][4*kg+i] = sv2[i]; ssA[wid][4*kg+i] = ssv2[i]; }
  }
  __syncthreads();
#pragma unroll
  for (int i = 0; i < 4; ++i) {
    float st = 0.f, sst = 0.f;
#pragma unroll
    for (int w = 0; w < 8; ++w) { st += sA[w][4*kg+i]; sst += ssA[w][4*kg+i]; }
    mu[i] = st*(1.f/160.f);
    float var = sst*(1.f/160.f) - mu[i]*mu[i];
    rs[i] = rsqrtf(var + 1e-5f);
  }
#pragma unroll
  for (int u = 0; u < 2; ++u)
    if (u < ntP) {
      int n = wid + 8*u;
      int col = n*16 + r15;
      float gv = gn[col], bv = btn[col];
#pragma unroll
      for (int i = 0; i < 4; ++i) {
        int row = 4*kg + i;
        int byte = row*384 + ((col*2) ^ ((row & 7) << 4));
        *(unsigned short*)(L1 + byte) = f2bf((fnv[u][i] - mu[i])*rs[i]*gv + bv);
      }
    }
  __syncthreads();

  qkv_from_L1(L1, wqkvN, bqkvN, qbN, TRANSV_NEXT, row0, wid, r15, kg);
}

// ---------------- first QKV for fallback path ----------------
__global__ __launch_bounds__(512)
void qkv0_kernel(const unsigned short* __restrict__ xn,
                 const unsigned short* __restrict__ wt_attn, const float* __restrict__ attn_b,
                 unsigned short* __restrict__ qbA) {
  __shared__ unsigned short L1s[16*192];
  char* L1 = (char*)L1s;
  int tid = threadIdx.x;
  int wid = tid >> 6, lane = tid & 63;
  int r15 = lane & 15, kg = lane >> 4;
  int row0 = blockIdx.x * 16;
  for (int k = tid; k < 16*DIMS_; k += 512) {
    int row = k / DIMS_, col = k - row*DIMS_;
    int byte = row*384 + ((col*2) ^ ((row & 7) << 4));
    *(unsigned short*)(L1 + byte) = xn[(size_t)(row0 + row)*DIMS_ + col];
  }
  __syncthreads();
  qkv_from_L1(L1, wt_attn, attn_b, qbA, true, row0, wid, r15, kg);
}

// ---------------- final projection ----------------
__global__ __launch_bounds__(256)
void out_kernel(const float* __restrict__ pf, const float* __restrict__ outW,
                const float* __restrict__ outB, const int* __restrict__ pk,
                float* __restrict__ out) {
  int idx = blockIdx.x*256 + threadIdx.x;
  if (idx >= BB*12*NNODES) return;
  int n = idx % NNODES;
  int rest = idx / NNODES;
  int o = rest % 12;
  int b = rest / 12;
  int row = b*PBB + pk[n];
  const float4* Pr = (const float4*)&pf[(size_t)row*DIMS_];
  const float4* Wr = (const float4*)&outW[o*DIMS_];
  float ax=0.f, ay=0.f, az=0.f, aw=0.f;
#pragma unroll
  for (int d4 = 0; d4 < 40; ++d4) {
    float4 a = Pr[d4], c = Wr[d4];
    ax += a.x*c.x; ay += a.y*c.y; az += a.z*c.z; aw += a.w*c.w;
  }
  out[idx] = (ax+ay+az+aw) + outB[o];
}

extern "C" void kernel_launch(void* const* d_in, const int* in_sizes, int n_in,
                              void* d_out, int out_size, void* d_ws, size_t ws_size,
                              hipStream_t stream) {
  const float* x         = (const float*)d_in[0];
  const int*   te        = (const int*)d_in[1];
  const float* patch_emb = (const float*)d_in[2];
  const float* node_tab  = (const float*)d_in[3];
  const float* tod_emb   = (const float*)d_in[4];
  const float* dow_emb   = (const float*)d_in[5];
  const float* conv_W    = (const float*)d_in[6];
  const float* conv_b    = (const float*)d_in[7];
  const float* ln_scale  = (const float*)d_in[8];
  const float* ln_bias   = (const float*)d_in[9];
  const float* attn_W    = (const float*)d_in[10];
  const float* attn_b    = (const float*)d_in[11];
  const float* mlp_W1    = (const float*)d_in[12];
  const float* mlp_b1    = (const float*)d_in[13];
  const float* mlp_W2    = (const float*)d_in[14];
  const float* mlp_b2    = (const float*)d_in[15];
  const float* out_W     = (const float*)d_in[16];
  const float* out_b     = (const float*)d_in[17];

  float* out = (float*)d_out;
  float* probs_st = out + BB*12*NNODES;

  const size_t CY = (size_t)(RMAX2 + 16) * DIMS_;        // q/k/v slice stride (ushorts)
  const size_t QBSZ = 2*CY + (size_t)DIMS_*RMAXP;        // one q/k/vt buffer (ushorts)

  char* W = (char*)d_ws;
  float* pf = (float*)W;                        W += (size_t)(RMAX2 + 16)*DIMS_*4;
  unsigned short* xn = (unsigned short*)W;      W += (size_t)(RMAX2 + 16)*DIMS_*2;
  unsigned short* qbA = (unsigned short*)W;     W += QBSZ*2;
  unsigned short* qbB = (unsigned short*)W;     W += QBSZ*2;
  unsigned short* wt_attn = (unsigned short*)W; W += (size_t)24*160*160*2;
  unsigned short* wt_w1   = (unsigned short*)W; W += (size_t)6*320*160*2;
  unsigned short* wt_w2   = (unsigned short*)W; W += (size_t)6*160*320*2;
  float* nsoft = (float*)W;                     W += (size_t)NNODES*32*4;
  int* flags = (int*)W;                         W += (size_t)6*GXNUM*4;
  int* pk   = (int*)W;
  int* cnt  = pk + NNODES;
  int* offs = cnt + 8;

  {
    int n4 = (RMAX2 + 16) * DIMS_ / 4;
    zero_pf<<<(n4 + 255)/256, 256, 0, stream>>>((float4*)pf, n4);
  }
  zero_flags<<<(6*GXNUM + 255)/256, 256, 0, stream>>>(flags, 6*GXNUM);
  cvt_all<<<dim3(50, 36), 256, 0, stream>>>(attn_W, mlp_W1, mlp_W2, wt_attn, wt_w1, wt_w2);
  patch_scan<<<1, 1024, 0, stream>>>(node_tab, patch_emb, probs_st, nsoft, pk, cnt, offs);
  embed_kernel<<<dim3(NNODES, BB), 160, 0, stream>>>(x, te, conv_W, conv_b, tod_emb, dow_emb,
                                                     nsoft, pk, ln_scale, ln_bias, pf, xn);

  // try cooperative persistent path (co-residency guarantee for spin-waits)
  int maxb = 0;
  hipError_t occ = hipOccupancyMaxActiveBlocksPerMultiprocessor(&maxb, (const void*)layers_coop, 512, 0);
  bool coop_ok = (occ == hipSuccess) && (maxb * 256 >= GXNUM);

  if (coop_ok) {
    void* args[] = {(void*)&qbA, (void*)&qbB, (void*)&wt_attn, (void*)&wt_w1, (void*)&wt_w2,
                    (void*)&attn_b, (void*)&mlp_b1, (void*)&mlp_b2,
                    (void*)&ln_scale, (void*)&ln_bias, (void*)&xn, (void*)&pf,
                    (void*)&cnt, (void*)&offs, (void*)&flags};
    hipError_t e = hipLaunchCooperativeKernel((const void*)layers_coop,
                                              dim3(GXNUM), dim3(512), args, 0, stream);
    coop_ok = (e == hipSuccess);
  }

  if (!coop_ok) {
    // fallback: per-layer launches with double-buffered QKV
    qkv0_kernel<<<GXNUM, 512, 0, stream>>>(xn, wt_attn, attn_b, qbA);
    for (int wb = 0; wb < 6; ++wb) {
      unsigned short* qbCur = (wb & 1) ? qbB : qbA;
      unsigned short* qbNext = (wb & 1) ? qbA : qbB;
      const unsigned short* wqkv = wt_attn + (size_t)wb*4*25600;
      const float* bbase = attn_b + (size_t)wb*4*DIMS_;
      const unsigned short* wproj = wqkv + 3*25600;
      const float* bproj = bbase + 3*DIMS_;
      const unsigned short* w1 = wt_w1 + (size_t)wb*51200;
      const unsigned short* w2 = wt_w2 + (size_t)wb*51200;
      const float* b1v = mlp_b1 + (size_t)wb*HID_;
      const float* b2v = mlp_b2 + (size_t)wb*DIMS_;
      const float* g1  = ln_scale + (size_t)(2*wb + 1)*DIMS_;
      const float* bt1 = ln_bias  + (size_t)(2*wb + 1)*DIMS_;
      const float* gn  = ln_scale + (size_t)(2*wb + 2)*DIMS_;
      const float* btn = ln_bias  + (size_t)(2*wb + 2)*DIMS_;
      const unsigned short* wqkvN = wt_attn + (size_t)(wb+1)*4*25600;
      const float* bqkvN = attn_b + (size_t)(wb+1)*4*DIMS_;
      if (wb == 5)
        fused_layer<false,false,false><<<GXNUM, 512, 0, stream>>>(
            qbCur, qbCur + CY, qbCur + 2*CY, wproj, bproj, w1, b1v, w2, b2v,
            g1, bt1, nullptr, nullptr, nullptr, nullptr, pf, qbNext, cnt, offs);
      else if ((wb & 1) == 0)
        fused_layer<true,true,false><<<GXNUM, 512, 0, stream>>>(
            qbCur, qbCur + CY, qbCur + 2*CY, wproj, bproj, w1, b1v, w2, b2v,
            g1, bt1, gn, btn, wqkvN, bqkvN, pf, qbNext, cnt, offs);
      else
        fused_layer<false,true,true><<<GXNUM, 512, 0, stream>>>(
            qbCur, qbCur + CY, qbCur + 2*CY, wproj, bproj, w1, b1v, w2, b2v,
            g1, bt1, gn, btn, wqkvN, bqkvN, pf, qbNext, cnt, offs);
    }
  }

  out_kernel<<<(BB*12*NNODES + 255)/256, 256, 0, stream>>>(pf, out_W, out_b, pk, out);
}

// Round 19
// 258.828 us; speedup vs baseline: 1.0179x; 1.0179x over previous
//
#include <hip/hip_runtime.h>
#include <hip/hip_cooperative_groups.h>
#include <math.h>

#define NNODES 883
#define BB 8
#define DIMS_ 160
#define HID_ 320
#define PBB 1008                // padded rows per batch (patch offsets aligned to 16)
#define RMAX2 (BB*PBB)          // 8064 packed rows incl. padding
#define RMAXP (RMAX2+64)        // vt row stride
#define GXNUM (RMAX2/16)        // 504 row tiles

typedef __attribute__((ext_vector_type(8))) short short8v;   // 8 bf16 in 4 VGPRs
typedef __attribute__((ext_vector_type(4))) float fx4;
typedef __attribute__((ext_vector_type(4))) unsigned short ushort4v;

__device__ __forceinline__ unsigned short f2bf(float f) {
  unsigned int u = __float_as_uint(f);
  u = (u + 0x7fffu + ((u >> 16) & 1u)) >> 16;   // RNE
  return (unsigned short)u;
}
__device__ __forceinline__ float bf2f(unsigned short u) {
  return __uint_as_float(((unsigned int)u) << 16);
}
__device__ __forceinline__ float gelu_f(float v) {
  return 0.5f*v*(1.f + erff(v*0.70710678118654752f));
}

// ---------------- cheap pf zeroing ----------------
__global__ __launch_bounds__(256)
void zero_pf(float4* __restrict__ p, int n4) {
  int i = blockIdx.x*256 + threadIdx.x;
  if (i < n4) p[i] = float4{0.f, 0.f, 0.f, 0.f};
}

// ---------------- flags zeroing (per replay) ----------------
__global__ __launch_bounds__(256)
void zero_flags(int* __restrict__ f, int n) {
  int i = blockIdx.x*256 + threadIdx.x;
  if (i < n) f[i] = 0;
}

// ---------------- patch assignment + ballot-prefix scan in one block ----------------
__global__ __launch_bounds__(1024)
void patch_scan(const float* __restrict__ node_table,
                const float* __restrict__ patch_emb,
                float* __restrict__ probs_st,
                float* __restrict__ nsoft,
                int* __restrict__ pk, int* __restrict__ cnt,
                int* __restrict__ offs, int* __restrict__ invp) {
  __shared__ float pe[256];
  __shared__ int wtot[8][16], woff[8][16];
  __shared__ int offs_s[8];
  int t = threadIdx.x;
  int wv = t >> 6, lane = t & 63;
  for (int k = t; k < 256; k += 1024) pe[k] = patch_emb[k];
  if (t < PBB) invp[t] = -1;
  __syncthreads();
  int am = -1;
  if (t < NNODES) {
    float nt[32];
#pragma unroll
    for (int j = 0; j < 32; ++j) nt[j] = node_table[t*32 + j];
    float lg[8];
#pragma unroll
    for (int r = 0; r < 8; ++r) {
      float a = 0.f;
#pragma unroll
      for (int j = 0; j < 32; ++j) a += nt[j] * pe[r*32 + j];
      lg[r] = a;
    }
    float m = lg[0];
#pragma unroll
    for (int r = 1; r < 8; ++r) m = fmaxf(m, lg[r]);
    float e[8]; float s = 0.f;
#pragma unroll
    for (int r = 0; r < 8; ++r) { e[r] = expf(lg[r] - m); s += e[r]; }
    float p[8];
#pragma unroll
    for (int r = 0; r < 8; ++r) p[r] = e[r] / s;
    am = 0; float best = p[0];
#pragma unroll
    for (int r = 1; r < 8; ++r) if (p[r] > best) { best = p[r]; am = r; }
#pragma unroll
    for (int r = 0; r < 8; ++r) {
      float hard = (r == am) ? 1.f : 0.f;
      probs_st[t*8 + r] = (hard - p[r]) + p[r];
    }
#pragma unroll
    for (int j = 0; j < 32; ++j) {
      float a = 0.f;
#pragma unroll
      for (int r = 0; r < 8; ++r) a += p[r] * pe[r*32 + j];
      nsoft[t*32 + j] = a;
    }
  }
  // ballot-based prefix within wave, per patch
  unsigned long long lt = (lane == 63) ? 0x7fffffffffffffffull : ((1ull << lane) - 1ull);
  int myprefix = 0;
#pragma unroll
  for (int r = 0; r < 8; ++r) {
    unsigned long long bm = __ballot(am == r);
    if (lane == 0) wtot[r][wv] = __popcll(bm);
    if (am == r) myprefix = __popcll(bm & lt);
  }
  __syncthreads();
  if (t < 128) {
    int r = t >> 4, w0 = t & 15;
    int s = 0;
    for (int w = 0; w < w0; ++w) s += wtot[r][w];
    woff[r][w0] = s;
  }
  __syncthreads();
  if (t == 0) {
    int o = 0;
#pragma unroll
    for (int r = 0; r < 8; ++r) {
      int c = woff[r][15] + wtot[r][15];
      offs_s[r] = o; offs[r] = o; cnt[r] = c;
      o += (c + 15) & ~15;
    }
  }
  __syncthreads();
  if (t < NNODES) {
    int pos = woff[am][wv] + myprefix;
    int pkv = offs_s[am] + pos;
    pk[t] = pkv;
    invp[pkv] = t;
  }
}

// ---------------- embedding + fused LN0 -> pf (f32) and xn (bf16) ----------------
__global__ __launch_bounds__(160)
void embed_kernel(const float* __restrict__ x, const int* __restrict__ te,
                  const float* __restrict__ convW, const float* __restrict__ convB,
                  const float* __restrict__ tod, const float* __restrict__ dow,
                  const float* __restrict__ nsoft, const int* __restrict__ pk,
                  const float* __restrict__ g, const float* __restrict__ bt,
                  float* __restrict__ pf, unsigned short* __restrict__ xn) {
  int n = blockIdx.x, b = blockIdx.y, t = threadIdx.x;
  __shared__ float xs[3][12];
  __shared__ float rsum[160], rss[160];
  __shared__ float musv[2];
  if (t < 12) {
    int l = t;
    xs[0][l] = x[(b*12 + l)*NNODES + n];
    int base = ((b*12 + l)*NNODES + n)*2;
    xs[1][l] = (float)te[base]     / 288.0f;
    xs[2][l] = (float)te[base + 1] / 7.0f;
  }
  __syncthreads();
  int row = b*PBB + pk[n];
  float val;
  if (t < 64) {
    float a = convB[t];
#pragma unroll
    for (int c = 0; c < 3; ++c)
#pragma unroll
      for (int l = 0; l < 12; ++l)
        a += xs[c][l] * convW[t*36 + c*12 + l];
    val = a;
  } else if (t < 96) {
    int ti = te[((b*12 + 11)*NNODES + n)*2 + 0];
    val = tod[ti*32 + (t - 64)];
  } else if (t < 128) {
    int dw = te[((b*12 + 11)*NNODES + n)*2 + 1];
    val = dow[dw*32 + (t - 96)];
  } else {
    val = nsoft[n*32 + (t - 128)];
  }
  pf[row*DIMS_ + t] = val;
  rsum[t] = val; rss[t] = val*val;
  __syncthreads();
  if (t < 32) {
    float s = 0.f, ss = 0.f;
#pragma unroll
    for (int j = 0; j < 5; ++j) { s += rsum[t + 32*j]; ss += rss[t + 32*j]; }
    s  += __shfl_xor(s, 1, 32);  ss += __shfl_xor(ss, 1, 32);
    s  += __shfl_xor(s, 2, 32);  ss += __shfl_xor(ss, 2, 32);
    s  += __shfl_xor(s, 4, 32);  ss += __shfl_xor(ss, 4, 32);
    s  += __shfl_xor(s, 8, 32);  ss += __shfl_xor(ss, 8, 32);
    s  += __shfl_xor(s, 16, 32); ss += __shfl_xor(ss, 16, 32);
    if (t == 0) {
      float mu = s*(1.f/160.f);
      float var = ss*(1.f/160.f) - mu*mu;
      musv[0] = mu; musv[1] = rsqrtf(var + 1e-5f);
    }
  }
  __syncthreads();
  xn[(size_t)row*DIMS_ + t] = f2bf((val - musv[0])*musv[1]*g[t] + bt[t]);
}

// ---------------- all weight converts, 32x32 LDS tile transpose to bf16 [N][K] ----------------
__global__ __launch_bounds__(256)
void cvt_all(const float* __restrict__ attn_W, const float* __restrict__ mlp_W1,
             const float* __restrict__ mlp_W2,
             unsigned short* __restrict__ wt_attn, unsigned short* __restrict__ wt_w1,
             unsigned short* __restrict__ wt_w2) {
  int y = blockIdx.y;
  const float* src; unsigned short* dst; int K, N;
  if (y < 24)      { src = attn_W + (size_t)y*25600;        dst = wt_attn + (size_t)y*25600; K = 160; N = 160; }
  else if (y < 30) { int q = y-24; src = mlp_W1 + (size_t)q*160*320; dst = wt_w1 + (size_t)q*51200; K = 160; N = 320; }
  else             { int q = y-30; src = mlp_W2 + (size_t)q*320*160; dst = wt_w2 + (size_t)q*51200; K = 320; N = 160; }
  int tn = N >> 5, tk = K >> 5;
  int tile = blockIdx.x;
  if (tile >= tn*tk) return;
  int n0 = (tile % tn) << 5, k0 = (tile / tn) << 5;
  __shared__ unsigned short lds[32][33];
  int col = threadIdx.x & 31, rb = threadIdx.x >> 5;
#pragma unroll
  for (int rr = 0; rr < 4; ++rr) {
    int row = rb + 8*rr;
    lds[row][col] = f2bf(src[(size_t)(k0 + row)*N + n0 + col]);
  }
  __syncthreads();
#pragma unroll
  for (int rr = 0; rr < 4; ++rr) {
    int row = rb + 8*rr;
    dst[(size_t)(n0 + row)*K + k0 + col] = lds[col][row];
  }
}

// ---------------- QKV from swizzled L1 (30 tiles over 8 waves) ----------------
__device__ __forceinline__ void qkv_from_L1(const char* L1,
    const unsigned short* __restrict__ wq, const float* __restrict__ bq,
    unsigned short* __restrict__ qbN, bool transv,
    int row0, int wid, int r15, int kg) {
  constexpr size_t CY = (size_t)(RMAX2 + 16) * DIMS_;
  fx4 accq[4];
#pragma unroll
  for (int u = 0; u < 4; ++u) accq[u] = (fx4){0.f,0.f,0.f,0.f};
#pragma unroll
  for (int t = 0; t < 5; ++t) {
    short8v a4 = *(const short8v*)(const void*)(L1 + r15*384 + ((t*64 + kg*16) ^ ((r15 & 7) << 4)));
#pragma unroll
    for (int u = 0; u < 4; ++u) {
      int n = wid + 8*u;
      if (n < 30) {
        int z = n / 10, nn = n - z*10;
        short8v bfr = *(const short8v*)(const void*)
            (wq + (size_t)z*25600 + (size_t)(nn*16 + r15)*160 + t*32 + kg*8);
        accq[u] = __builtin_amdgcn_mfma_f32_16x16x32_bf16(a4, bfr, accq[u], 0, 0, 0);
      }
    }
  }
#pragma unroll
  for (int u = 0; u < 4; ++u) {
    int n = wid + 8*u;
    if (n >= 30) continue;
    int z = n / 10, nn = n - z*10;
    int col = nn*16 + r15;
    float bv = bq[z*160 + col];
    unsigned short* C = qbN + (size_t)z * CY;
#pragma unroll
    for (int i = 0; i < 4; ++i) {
      int rr = row0 + 4*kg + i;
      unsigned short h = f2bf(accq[u][i] + bv);
      if (transv && z == 2) C[(size_t)col*RMAXP + rr] = h;
      else                  C[(size_t)rr*DIMS_ + col] = h;
    }
  }
}

// ---------------- persistent cooperative kernel: QKV0 + 6 fused layers + output ----------------
__global__ __launch_bounds__(512, 4)
void layers_coop(unsigned short* __restrict__ qbA, unsigned short* __restrict__ qbB,
                 const unsigned short* __restrict__ wt_attn,
                 const unsigned short* __restrict__ wt_w1,
                 const unsigned short* __restrict__ wt_w2,
                 const float* __restrict__ attn_b, const float* __restrict__ mlp_b1,
                 const float* __restrict__ mlp_b2,
                 const float* __restrict__ ln_scale, const float* __restrict__ ln_bias,
                 const unsigned short* __restrict__ xn, float* __restrict__ pf,
                 const int* __restrict__ cnt, const int* __restrict__ offs,
                 int* __restrict__ flags, const int* __restrict__ invp,
                 const float* __restrict__ outW, const float* __restrict__ outB,
                 float* __restrict__ outp) {
  constexpr size_t CY = (size_t)(RMAX2 + 16) * DIMS_;
  __shared__ unsigned short L1s[16*192];
  __shared__ unsigned short L2s[16*320];
  __shared__ float sA[8][16], ssA[8][16];
  __shared__ float Sf[16*256];
  __shared__ unsigned short Pl[16*256];
  __shared__ float Sinv[16];
  __shared__ int cs[8], os[8];
  char* L1 = (char*)L1s; char* L2 = (char*)L2s; char* Pb = (char*)Pl;
  const float scale = 0.07905694150420949f;

  int tid = threadIdx.x;
  int wid = tid >> 6;
  int lane = tid & 63;
  int r15 = lane & 15, kg = lane >> 4;
  int row0 = blockIdx.x * 16;
  if (tid < 8) { cs[tid] = cnt[tid]; os[tid] = offs[tid]; }
  __syncthreads();
  int b = row0 / PBB;
  int local = row0 - b*PBB;
  int r = 7;
#pragma unroll
  for (int rr = 6; rr >= 0; --rr) if (local < os[rr+1]) r = rr;
  int L = cs[r];
  int q0 = local - os[r];
  int bo = b*PBB + os[r];
  int ntP = (wid < 2) ? 2 : 1;
  int ntM = (wid < 4) ? 3 : 2;

  // ---- trunk registers
  float trunk[2][4];
#pragma unroll
  for (int u = 0; u < 2; ++u)
    if (u < ntP) {
      int col = (wid + 8*u)*16 + r15;
#pragma unroll
      for (int i = 0; i < 4; ++i)
        trunk[u][i] = pf[(size_t)(row0 + 4*kg + i)*DIMS_ + col];
    }

  // ---- pre-phase: QKV0 from xn, V transposed (layer 0 intra)
  for (int k = tid; k < 16*DIMS_; k += 512) {
    int row = k / DIMS_, col = k - row*DIMS_;
    int byte = row*384 + ((col*2) ^ ((row & 7) << 4));
    *(unsigned short*)(L1 + byte) = xn[(size_t)(row0 + row)*DIMS_ + col];
  }
  __syncthreads();
  qkv_from_L1(L1, wt_attn, attn_b, qbA, true, row0, wid, r15, kg);
  __threadfence();
  __syncthreads();
  if (tid == 0)
    __hip_atomic_store(&flags[0*GXNUM + (int)blockIdx.x], 1, __ATOMIC_RELEASE, __HIP_MEMORY_SCOPE_AGENT);

  for (int wb = 0; wb < 6; ++wb) {
    bool intra = ((wb & 1) == 0);
    bool hasnext = (wb < 5);
    unsigned short* qbCur = (wb & 1) ? qbB : qbA;
    unsigned short* qbNext = (wb & 1) ? qbA : qbB;
    const unsigned short* qb = qbCur;
    const unsigned short* kb = qbCur + CY;
    const unsigned short* vt = qbCur + 2*CY;
    const unsigned short* wqkv = wt_attn + (size_t)wb*4*25600;
    const float* bbase = attn_b + (size_t)wb*4*DIMS_;
    const unsigned short* wproj = wqkv + 3*25600;
    const float* bproj = bbase + 3*DIMS_;
    const unsigned short* w1 = wt_w1 + (size_t)wb*51200;
    const unsigned short* w2 = wt_w2 + (size_t)wb*51200;
    const float* b1v = mlp_b1 + (size_t)wb*HID_;
    const float* b2v = mlp_b2 + (size_t)wb*DIMS_;
    const float* g1  = ln_scale + (size_t)(2*wb + 1)*DIMS_;
    const float* bt1 = ln_bias  + (size_t)(2*wb + 1)*DIMS_;
    const float* gn  = ln_scale + (size_t)(2*wb + 2)*DIMS_;
    const float* btn = ln_bias  + (size_t)(2*wb + 2)*DIMS_;
    const unsigned short* wqkvN = wt_attn + (size_t)(wb+1)*4*25600;
    const float* bqkvN = attn_b + (size_t)(wb+1)*4*DIMS_;

    // ---- dataflow wait: QKV deps of layer wb
    {
      const int fbase = wb*GXNUM;
      if (intra) {
        int nkt = (L + 15) >> 4;
        int blk0 = bo >> 4;
        if (tid < nkt) {
          while (__hip_atomic_load(&flags[fbase + blk0 + tid], __ATOMIC_RELAXED, __HIP_MEMORY_SCOPE_AGENT) == 0) {}
        }
      } else {
        if (tid < 8 && q0 < cs[tid]) {
          int dep = (b*PBB + os[tid] + q0) >> 4;
          while (__hip_atomic_load(&flags[fbase + dep], __ATOMIC_RELAXED, __HIP_MEMORY_SCOPE_AGENT) == 0) {}
        }
      }
      __syncthreads();
      __threadfence();
    }

    // =================== attention -> ab in L1 ===================
    if (intra) {
      int nkt = (L + 15) >> 4;
      int npv = (L + 31) >> 5;
      short8v qf[5];
      {
        const unsigned short* Qr = qb + (size_t)(row0 + r15)*DIMS_ + kg*8;
#pragma unroll
        for (int kk = 0; kk < 5; ++kk) qf[kk] = *(const short8v*)(const void*)(Qr + kk*32);
      }
#pragma unroll
      for (int u = 0; u < 2; ++u) {
        int t = wid + 8*u;
        if (t < nkt) {
          fx4 a = (fx4){0.f,0.f,0.f,0.f};
          const unsigned short* Kr = kb + (size_t)(bo + t*16 + r15)*DIMS_ + kg*8;
#pragma unroll
          for (int kk = 0; kk < 5; ++kk) {
            short8v kf = *(const short8v*)(const void*)(Kr + kk*32);
            a = __builtin_amdgcn_mfma_f32_16x16x32_bf16(qf[kk], kf, a, 0, 0, 0);
          }
          int j = t*16 + r15;
#pragma unroll
          for (int i = 0; i < 4; ++i)
            Sf[(4*kg + i)*256 + j] = (j < L) ? a[i]*scale : -1e30f;
        }
      }
      __syncthreads();
      {
        int qq = lane >> 5, l32 = lane & 31;
        int row = 2*wid + qq;
        float vals[8];
        float mx = -1e30f;
#pragma unroll
        for (int k = 0; k < 8; ++k) {
          int j = l32 + 32*k;
          float v = (j < L) ? Sf[row*256 + j] : -1e30f;
          vals[k] = v; mx = fmaxf(mx, v);
        }
        mx = fmaxf(mx, __shfl_xor(mx, 1, 32));
        mx = fmaxf(mx, __shfl_xor(mx, 2, 32));
        mx = fmaxf(mx, __shfl_xor(mx, 4, 32));
        mx = fmaxf(mx, __shfl_xor(mx, 8, 32));
        mx = fmaxf(mx, __shfl_xor(mx, 16, 32));
        float sum = 0.f;
#pragma unroll
        for (int k = 0; k < 8; ++k) {
          float e = (vals[k] > -1e29f) ? expf(vals[k] - mx) : 0.f;
          vals[k] = e; sum += e;
        }
        sum += __shfl_xor(sum, 1, 32);
        sum += __shfl_xor(sum, 2, 32);
        sum += __shfl_xor(sum, 4, 32);
        sum += __shfl_xor(sum, 8, 32);
        sum += __shfl_xor(sum, 16, 32);
        if (l32 == 0) Sinv[row] = (sum > 0.f) ? 1.f/sum : 0.f;
#pragma unroll
        for (int k = 0; k < 8; ++k) {
          int j = l32 + 32*k;
          int byte = row*512 + ((j*2) ^ ((row & 7) << 4));
          *(unsigned short*)(Pb + byte) = f2bf(vals[k]);
        }
      }
      __syncthreads();
      fx4 o[2];
#pragma unroll
      for (int u = 0; u < 2; ++u) o[u] = (fx4){0.f,0.f,0.f,0.f};
#pragma unroll
      for (int sS = 0; sS < 8; ++sS) {
        if (sS < npv) {
          short8v pfr = *(const short8v*)(const void*)
              (Pb + r15*512 + ((sS*64 + kg*16) ^ ((r15 & 7) << 4)));
#pragma unroll
          for (int u = 0; u < 2; ++u)
            if (u < ntP) {
              int n = wid + 8*u;
              const unsigned short* Vr = vt + (size_t)(n*16 + r15)*RMAXP + bo + sS*32 + kg*8;
              short8v vf = *(const short8v*)(const void*)Vr;
              o[u] = __builtin_amdgcn_mfma_f32_16x16x32_bf16(pfr, vf, o[u], 0, 0, 0);
            }
        }
      }
      float inv[4];
#pragma unroll
      for (int i = 0; i < 4; ++i) inv[i] = Sinv[4*kg + i];
#pragma unroll
      for (int u = 0; u < 2; ++u)
        if (u < ntP) {
          int n = wid + 8*u;
#pragma unroll
          for (int i = 0; i < 4; ++i) {
            int row = 4*kg + i, d = n*16 + r15;
            int byte = row*384 + ((d*2) ^ ((row & 7) << 4));
            *(unsigned short*)(L1 + byte) = f2bf(o[u][i]*inv[i]);
          }
        }
    } else {
      int qq = lane >> 5, l32 = lane & 31;
      int rowT = 2*wid + qq;
      int p = q0 + rowT;
      bool vq = p < L;
      int j = l32 >> 2, c = l32 & 3;
      int cj = cs[j];
      bool vk = p < cj;
      int keyrow = b*PBB + os[j] + (vk ? p : 0);
      int qrow = row0 + rowT;
      float part = 0.f;
      {
        const unsigned short* qr = qb + (size_t)qrow*DIMS_ + c*40;
        const unsigned short* kr = kb + (size_t)keyrow*DIMS_ + c*40;
#pragma unroll
        for (int dd = 0; dd < 5; ++dd) {
          short8v a8 = *(const short8v*)(const void*)(qr + dd*8);
          short8v b8 = *(const short8v*)(const void*)(kr + dd*8);
#pragma unroll
          for (int u = 0; u < 8; ++u)
            part += bf2f((unsigned short)a8[u]) * bf2f((unsigned short)b8[u]);
        }
      }
      part += __shfl_xor(part, 1, 4);
      part += __shfl_xor(part, 2, 4);
      float sc = (vq && vk) ? part*scale : -1e30f;
      float m = sc;
      m = fmaxf(m, __shfl_xor(m, 4, 32));
      m = fmaxf(m, __shfl_xor(m, 8, 32));
      m = fmaxf(m, __shfl_xor(m, 16, 32));
      float e = (vq && vk) ? expf(sc - m) : 0.f;
      float sum = e;
      sum += __shfl_xor(sum, 4, 32);
      sum += __shfl_xor(sum, 8, 32);
      sum += __shfl_xor(sum, 16, 32);
      float w = (vq && vk && sum > 0.f) ? e/sum : 0.f;
      float o[5];
#pragma unroll
      for (int k = 0; k < 5; ++k) o[k] = 0.f;
      int qbase = qq*32;
#pragma unroll
      for (int jj = 0; jj < 8; ++jj) {
        float wv = __shfl(w, qbase + jj*4);
        int kr2 = __shfl(keyrow, qbase + jj*4);
        if (wv > 0.f) {
          const unsigned short* Vr = vt + (size_t)kr2*DIMS_;
#pragma unroll
          for (int k = 0; k < 5; ++k) o[k] += wv * bf2f(Vr[l32 + 32*k]);
        }
      }
#pragma unroll
      for (int k = 0; k < 5; ++k) {
        int d = l32 + 32*k;
        int byte = rowT*384 + ((d*2) ^ ((rowT & 7) << 4));
        *(unsigned short*)(L1 + byte) = f2bf(vq ? o[k] : 0.f);
      }
    }
    __syncthreads();

    // =================== phase 1: proj (trunk in registers) ===================
    short8v af[5];
#pragma unroll
    for (int t = 0; t < 5; ++t)
      af[t] = *(const short8v*)(const void*)(L1 + r15*384 + ((t*64 + kg*16) ^ ((r15 & 7) << 4)));
    fx4 acc[2];
#pragma unroll
    for (int u = 0; u < 2; ++u) acc[u] = (fx4){0.f,0.f,0.f,0.f};
#pragma unroll
    for (int t = 0; t < 5; ++t)
#pragma unroll
      for (int u = 0; u < 2; ++u)
        if (u < ntP) {
          int n = wid + 8*u;
          short8v bfr = *(const short8v*)(const void*)(wproj + (size_t)(n*16 + r15)*160 + t*32 + kg*8);
          acc[u] = __builtin_amdgcn_mfma_f32_16x16x32_bf16(af[t], bfr, acc[u], 0, 0, 0);
        }

    float sv[4] = {0,0,0,0}, ssv[4] = {0,0,0,0};
#pragma unroll
    for (int u = 0; u < 2; ++u)
      if (u < ntP) {
        int n = wid + 8*u;
        int col = n*16 + r15;
        float bv = bproj[col];
#pragma unroll
        for (int i = 0; i < 4; ++i) {
          float v = trunk[u][i] + acc[u][i] + bv;
          trunk[u][i] = v;
          sv[i] += v; ssv[i] += v*v;
        }
      }
#pragma unroll
    for (int i = 0; i < 4; ++i) {
      sv[i] += __shfl_xor(sv[i], 1, 16); ssv[i] += __shfl_xor(ssv[i], 1, 16);
      sv[i] += __shfl_xor(sv[i], 2, 16); ssv[i] += __shfl_xor(ssv[i], 2, 16);
      sv[i] += __shfl_xor(sv[i], 4, 16); ssv[i] += __shfl_xor(ssv[i], 4, 16);
      sv[i] += __shfl_xor(sv[i], 8, 16); ssv[i] += __shfl_xor(ssv[i], 8, 16);
    }
    if (r15 == 0) {
#pragma unroll
      for (int i = 0; i < 4; ++i) { sA[wid][4*kg+i] = sv[i]; ssA[wid][4*kg+i] = ssv[i]; }
    }
    __syncthreads();
    float mu[4], rs[4];
#pragma unroll
    for (int i = 0; i < 4; ++i) {
      float st = 0.f, sst = 0.f;
#pragma unroll
      for (int w = 0; w < 8; ++w) { st += sA[w][4*kg+i]; sst += ssA[w][4*kg+i]; }
      mu[i] = st*(1.f/160.f);
      float var = sst*(1.f/160.f) - mu[i]*mu[i];
      rs[i] = rsqrtf(var + 1e-5f);
    }
#pragma unroll
    for (int u = 0; u < 2; ++u)
      if (u < ntP) {
        int n = wid + 8*u;
        int col = n*16 + r15;
        float gv = g1[col], bv = bt1[col];
#pragma unroll
        for (int i = 0; i < 4; ++i) {
          int row = 4*kg + i;
          int byte = row*384 + ((col*2) ^ ((row & 7) << 4));
          *(unsigned short*)(L1 + byte) = f2bf((trunk[u][i] - mu[i])*rs[i]*gv + bv);
        }
      }
    __syncthreads();

    // =================== phase 2: MLP1 + gelu -> L2 ===================
    fx4 acc2[3];
#pragma unroll
    for (int u = 0; u < 3; ++u) acc2[u] = (fx4){0.f,0.f,0.f,0.f};
#pragma unroll
    for (int t = 0; t < 5; ++t) {
      short8v a2 = *(const short8v*)(const void*)(L1 + r15*384 + ((t*64 + kg*16) ^ ((r15 & 7) << 4)));
#pragma unroll
      for (int u = 0; u < 3; ++u)
        if (u < ntM) {
          int n = wid + 8*u;
          short8v bfr = *(const short8v*)(const void*)(w1 + (size_t)(n*16 + r15)*160 + t*32 + kg*8);
          acc2[u] = __builtin_amdgcn_mfma_f32_16x16x32_bf16(a2, bfr, acc2[u], 0, 0, 0);
        }
    }
#pragma unroll
    for (int u = 0; u < 3; ++u)
      if (u < ntM) {
        int n = wid + 8*u;
        int col = n*16 + r15;
        float bv = b1v[col];
#pragma unroll
        for (int i = 0; i < 4; ++i) {
          float v = gelu_f(acc2[u][i] + bv);
          int row = 4*kg + i;
          int byte = row*640 + ((col*2) ^ ((row & 7) << 4));
          *(unsigned short*)(L2 + byte) = f2bf(v);
        }
      }
    __syncthreads();

    // =================== phase 3: MLP2 + residual (trunk) ===================
    fx4 acc3[2];
#pragma unroll
    for (int u = 0; u < 2; ++u) acc3[u] = (fx4){0.f,0.f,0.f,0.f};
#pragma unroll
    for (int t = 0; t < 10; ++t) {
      short8v a3 = *(const short8v*)(const void*)(L2 + r15*640 + ((t*64 + kg*16) ^ ((r15 & 7) << 4)));
#pragma unroll
      for (int u = 0; u < 2; ++u)
        if (u < ntP) {
          int n = wid + 8*u;
          short8v bfr = *(const short8v*)(const void*)(w2 + (size_t)(n*16 + r15)*320 + t*32 + kg*8);
          acc3[u] = __builtin_amdgcn_mfma_f32_16x16x32_bf16(a3, bfr, acc3[u], 0, 0, 0);
        }
    }
    float sv2[4] = {0,0,0,0}, ssv2[4] = {0,0,0,0};
#pragma unroll
    for (int u = 0; u < 2; ++u)
      if (u < ntP) {
        int n = wid + 8*u;
        int col = n*16 + r15;
        float bv = b2v[col];
#pragma unroll
        for (int i = 0; i < 4; ++i) {
          float v = trunk[u][i] + acc3[u][i] + bv;
          trunk[u][i] = v;
          sv2[i] += v; ssv2[i] += v*v;
        }
      }

    if (hasnext) {
      // =================== phase 4: LN_next -> L1 ===================
#pragma unroll
      for (int i = 0; i < 4; ++i) {
        sv2[i] += __shfl_xor(sv2[i], 1, 16); ssv2[i] += __shfl_xor(ssv2[i], 1, 16);
        sv2[i] += __shfl_xor(sv2[i], 2, 16); ssv2[i] += __shfl_xor(ssv2[i], 2, 16);
        sv2[i] += __shfl_xor(sv2[i], 4, 16); ssv2[i] += __shfl_xor(ssv2[i], 4, 16);
        sv2[i] += __shfl_xor(sv2[i], 8, 16); ssv2[i] += __shfl_xor(ssv2[i], 8, 16);
      }
      __syncthreads();
      if (r15 == 0) {
#pragma unroll
        for (int i = 0; i < 4; ++i) { sA[wid][4*kg+i] = sv2[i]; ssA[wid][4*kg+i] = ssv2[i]; }
      }
      __syncthreads();
#pragma unroll
      for (int i = 0; i < 4; ++i) {
        float st = 0.f, sst = 0.f;
#pragma unroll
        for (int w = 0; w < 8; ++w) { st += sA[w][4*kg+i]; sst += ssA[w][4*kg+i]; }
        mu[i] = st*(1.f/160.f);
        float var = sst*(1.f/160.f) - mu[i]*mu[i];
        rs[i] = rsqrtf(var + 1e-5f);
      }
#pragma unroll
      for (int u = 0; u < 2; ++u)
        if (u < ntP) {
          int n = wid + 8*u;
          int col = n*16 + r15;
          float gv = gn[col], bv = btn[col];
#pragma unroll
          for (int i = 0; i < 4; ++i) {
            int row = 4*kg + i;
            int byte = row*384 + ((col*2) ^ ((row & 7) << 4));
            *(unsigned short*)(L1 + byte) = f2bf((trunk[u][i] - mu[i])*rs[i]*gv + bv);
          }
        }
      __syncthreads();

      // =================== phase 5: QKV_next + flag ===================
      qkv_from_L1(L1, wqkvN, bqkvN, qbNext, (wb & 1) != 0, row0, wid, r15, kg);
      __threadfence();
      __syncthreads();
      if (tid == 0)
        __hip_atomic_store(&flags[(wb+1)*GXNUM + (int)blockIdx.x], 1, __ATOMIC_RELEASE, __HIP_MEMORY_SCOPE_AGENT);
    }
  }

  // =================== epilogue: output projection from trunk ===================
  __syncthreads();   // prior LDS uses done
  float* So = Sf;                    // [16][164] padded
  float* Wl = (float*)Pl;            // [12][161] padded
#pragma unroll
  for (int u = 0; u < 2; ++u)
    if (u < ntP) {
      int col = (wid + 8*u)*16 + r15;
#pragma unroll
      for (int i = 0; i < 4; ++i)
        So[(4*kg + i)*164 + col] = trunk[u][i];
    }
  for (int k = tid; k < 12*160; k += 512) {
    int o = k / 160, d = k - o*160;
    Wl[o*161 + d] = outW[k];
  }
  __syncthreads();
  if (tid < 192) {
    int rr = tid / 12, o = tid - rr*12;
    int n = invp[local + rr];
    if (n >= 0) {
      float a = outB[o];
      const float* Sr = &So[rr*164];
      const float* Wr = &Wl[o*161];
#pragma unroll 8
      for (int d = 0; d < 160; ++d) a += Sr[d]*Wr[d];
      outp[(size_t)(b*12 + o)*NNODES + n] = a;
    }
  }
}

// ---------------- fallback: per-layer kernel ----------------
template<bool INTRA, bool HASNEXT, bool TRANSV_NEXT>
__global__ __launch_bounds__(512)
void fused_layer(const unsigned short* __restrict__ qb,
                 const unsigned short* __restrict__ kb,
                 const unsigned short* __restrict__ vt,
                 const unsigned short* __restrict__ wproj, const float* __restrict__ bproj,
                 const unsigned short* __restrict__ w1, const float* __restrict__ b1v,
                 const unsigned short* __restrict__ w2, const float* __restrict__ b2v,
                 const float* __restrict__ g1, const float* __restrict__ bt1,
                 const float* __restrict__ gn, const float* __restrict__ btn,
                 const unsigned short* __restrict__ wqkvN, const float* __restrict__ bqkvN,
                 float* __restrict__ pf, unsigned short* __restrict__ qbN,
                 const int* __restrict__ cnt, const int* __restrict__ offs) {
  __shared__ unsigned short L1s[16*192];
  __shared__ unsigned short L2s[16*320];
  __shared__ float sA[8][16], ssA[8][16];
  __shared__ float Sf[INTRA ? 16*256 : 1];
  __shared__ unsigned short Pl[INTRA ? 16*256 : 1];
  __shared__ float Sinv[16];
  __shared__ int cs[8], os[8];
  char* L1 = (char*)L1s; char* L2 = (char*)L2s; char* Pb = (char*)Pl;
  const float scale = 0.07905694150420949f;

  int tid = threadIdx.x;
  int wid = tid >> 6;
  int lane = tid & 63;
  int r15 = lane & 15, kg = lane >> 4;
  int row0 = blockIdx.x * 16;
  if (tid < 8) { cs[tid] = cnt[tid]; os[tid] = offs[tid]; }
  __syncthreads();
  int b = row0 / PBB;
  int local = row0 - b*PBB;
  int r = 7;
#pragma unroll
  for (int rr = 6; rr >= 0; --rr) if (local < os[rr+1]) r = rr;
  int L = cs[r];
  int q0 = local - os[r];
  int bo = b*PBB + os[r];
  int ntP = (wid < 2) ? 2 : 1;
  int ntM = (wid < 4) ? 3 : 2;

  if (INTRA) {
    int nkt = (L + 15) >> 4;
    int npv = (L + 31) >> 5;
    short8v qf[5];
    {
      const unsigned short* Qr = qb + (size_t)(row0 + r15)*DIMS_ + kg*8;
#pragma unroll
      for (int kk = 0; kk < 5; ++kk) qf[kk] = *(const short8v*)(const void*)(Qr + kk*32);
    }
#pragma unroll
    for (int u = 0; u < 2; ++u) {
      int t = wid + 8*u;
      if (t < nkt) {
        fx4 a = (fx4){0.f,0.f,0.f,0.f};
        const unsigned short* Kr = kb + (size_t)(bo + t*16 + r15)*DIMS_ + kg*8;
#pragma unroll
        for (int kk = 0; kk < 5; ++kk) {
          short8v kf = *(const short8v*)(const void*)(Kr + kk*32);
          a = __builtin_amdgcn_mfma_f32_16x16x32_bf16(qf[kk], kf, a, 0, 0, 0);
        }
        int j = t*16 + r15;
#pragma unroll
        for (int i = 0; i < 4; ++i)
          Sf[(4*kg + i)*256 + j] = (j < L) ? a[i]*scale : -1e30f;
      }
    }
    __syncthreads();
    {
      int qq = lane >> 5, l32 = lane & 31;
      int row = 2*wid + qq;
      float vals[8];
      float mx = -1e30f;
#pragma unroll
      for (int k = 0; k < 8; ++k) {
        int j = l32 + 32*k;
        float v = (j < L) ? Sf[row*256 + j] : -1e30f;
        vals[k] = v; mx = fmaxf(mx, v);
      }
      mx = fmaxf(mx, __shfl_xor(mx, 1, 32));
      mx = fmaxf(mx, __shfl_xor(mx, 2, 32));
      mx = fmaxf(mx, __shfl_xor(mx, 4, 32));
      mx = fmaxf(mx, __shfl_xor(mx, 8, 32));
      mx = fmaxf(mx, __shfl_xor(mx, 16, 32));
      float sum = 0.f;
#pragma unroll
      for (int k = 0; k < 8; ++k) {
        float e = (vals[k] > -1e29f) ? expf(vals[k] - mx) : 0.f;
        vals[k] = e; sum += e;
      }
      sum += __shfl_xor(sum, 1, 32);
      sum += __shfl_xor(sum, 2, 32);
      sum += __shfl_xor(sum, 4, 32);
      sum += __shfl_xor(sum, 8, 32);
      sum += __shfl_xor(sum, 16, 32);
      if (l32 == 0) Sinv[row] = (sum > 0.f) ? 1.f/sum : 0.f;
#pragma unroll
      for (int k = 0; k < 8; ++k) {
        int j = l32 + 32*k;
        int byte = row*512 + ((j*2) ^ ((row & 7) << 4));
        *(unsigned short*)(Pb + byte) = f2bf(vals[k]);
      }
    }
    __syncthreads();
    fx4 o[2];
#pragma unroll
    for (int u = 0; u < 2; ++u) o[u] = (fx4){0.f,0.f,0.f,0.f};
#pragma unroll
    for (int sS = 0; sS < 8; ++sS) {
      if (sS < npv) {
        short8v pfr = *(const short8v*)(const void*)
            (Pb + r15*512 + ((sS*64 + kg*16) ^ ((r15 & 7) << 4)));
#pragma unroll
        for (int u = 0; u < 2; ++u)
          if (u < ntP) {
            int n = wid + 8*u;
            const unsigned short* Vr = vt + (size_t)(n*16 + r15)*RMAXP + bo + sS*32 + kg*8;
            short8v vf = *(const short8v*)(const void*)Vr;
            o[u] = __builtin_amdgcn_mfma_f32_16x16x32_bf16(pfr, vf, o[u], 0, 0, 0);
          }
      }
    }
    float inv[4];
#pragma unroll
    for (int i = 0; i < 4; ++i) inv[i] = Sinv[4*kg + i];
#pragma unroll
    for (int u = 0; u < 2; ++u)
      if (u < ntP) {
        int n = wid + 8*u;
#pragma unroll
        for (int i = 0; i < 4; ++i) {
          int row = 4*kg + i, d = n*16 + r15;
          int byte = row*384 + ((d*2) ^ ((row & 7) << 4));
          *(unsigned short*)(L1 + byte) = f2bf(o[u][i]*inv[i]);
        }
      }
  } else {
    int qq = lane >> 5, l32 = lane & 31;
    int rowT = 2*wid + qq;
    int p = q0 + rowT;
    bool vq = p < L;
    int j = l32 >> 2, c = l32 & 3;
    int cj = cs[j];
    bool vk = p < cj;
    int keyrow = b*PBB + os[j] + (vk ? p : 0);
    int qrow = row0 + rowT;
    float part = 0.f;
    {
      const unsigned short* qr = qb + (size_t)qrow*DIMS_ + c*40;
      const unsigned short* kr = kb + (size_t)keyrow*DIMS_ + c*40;
#pragma unroll
      for (int dd = 0; dd < 5; ++dd) {
        short8v a8 = *(const short8v*)(const void*)(qr + dd*8);
        short8v b8 = *(const short8v*)(const void*)(kr + dd*8);
#pragma unroll
        for (int u = 0; u < 8; ++u)
          part += bf2f((unsigned short)a8[u]) * bf2f((unsigned short)b8[u]);
      }
    }
    part += __shfl_xor(part, 1, 4);
    part += __shfl_xor(part, 2, 4);
    float sc = (vq && vk) ? part*scale : -1e30f;
    float m = sc;
    m = fmaxf(m, __shfl_xor(m, 4, 32));
    m = fmaxf(m, __shfl_xor(m, 8, 32));
    m = fmaxf(m, __shfl_xor(m, 16, 32));
    float e = (vq && vk) ? expf(sc - m) : 0.f;
    float sum = e;
    sum += __shfl_xor(sum, 4, 32);
    sum += __shfl_xor(sum, 8, 32);
    sum += __shfl_xor(sum, 16, 32);
    float w = (vq && vk && sum > 0.f) ? e/sum : 0.f;
    float o[5];
#pragma unroll
    for (int k = 0; k < 5; ++k) o[k] = 0.f;
    int qbase = qq*32;
#pragma unroll
    for (int jj = 0; jj < 8; ++jj) {
      float wv = __shfl(w, qbase + jj*4);
      int kr2 = __shfl(keyrow, qbase + jj*4);
      if (wv > 0.f) {
        const unsigned short* Vr = vt + (size_t)kr2*DIMS_;
#pragma unroll
        for (int k = 0; k < 5; ++k) o[k] += wv * bf2f(Vr[l32 + 32*k]);
      }
    }
#pragma unroll
    for (int k = 0; k < 5; ++k) {
      int d = l32 + 32*k;
      int byte = rowT*384 + ((d*2) ^ ((rowT & 7) << 4));
      *(unsigned short*)(L1 + byte) = f2bf(vq ? o[k] : 0.f);
    }
  }
  __syncthreads();

  short8v af[5];
#pragma unroll
  for (int t = 0; t < 5; ++t)
    af[t] = *(const short8v*)(const void*)(L1 + r15*384 + ((t*64 + kg*16) ^ ((r15 & 7) << 4)));
  fx4 acc[2];
#pragma unroll
  for (int u = 0; u < 2; ++u) acc[u] = (fx4){0.f,0.f,0.f,0.f};
#pragma unroll
  for (int t = 0; t < 5; ++t)
#pragma unroll
    for (int u = 0; u < 2; ++u)
      if (u < ntP) {
        int n = wid + 8*u;
        short8v bfr = *(const short8v*)(const void*)(wproj + (size_t)(n*16 + r15)*160 + t*32 + kg*8);
        acc[u] = __builtin_amdgcn_mfma_f32_16x16x32_bf16(af[t], bfr, acc[u], 0, 0, 0);
      }

  float pn[2][4];
  float sv[4] = {0,0,0,0}, ssv[4] = {0,0,0,0};
#pragma unroll
  for (int u = 0; u < 2; ++u)
    if (u < ntP) {
      int n = wid + 8*u;
      int col = n*16 + r15;
      float bv = bproj[col];
#pragma unroll
      for (int i = 0; i < 4; ++i) {
        int row = row0 + 4*kg + i;
        float v = pf[(size_t)row*DIMS_ + col] + acc[u][i] + bv;
        pn[u][i] = v;
        pf[(size_t)row*DIMS_ + col] = v;
        sv[i] += v; ssv[i] += v*v;
      }
    }
#pragma unroll
  for (int i = 0; i < 4; ++i) {
    sv[i] += __shfl_xor(sv[i], 1, 16); ssv[i] += __shfl_xor(ssv[i], 1, 16);
    sv[i] += __shfl_xor(sv[i], 2, 16); ssv[i] += __shfl_xor(ssv[i], 2, 16);
    sv[i] += __shfl_xor(sv[i], 4, 16); ssv[i] += __shfl_xor(ssv[i], 4, 16);
    sv[i] += __shfl_xor(sv[i], 8, 16); ssv[i] += __shfl_xor(ssv[i], 8, 16);
  }
  if (r15 == 0) {
#pragma unroll
    for (int i = 0; i < 4; ++i) { sA[wid][4*kg+i] = sv[i]; ssA[wid][4*kg+i] = ssv[i]; }
  }
  __syncthreads();
  float mu[4], rs[4];
#pragma unroll
  for (int i = 0; i < 4; ++i) {
    float st = 0.f, sst = 0.f;
#pragma unroll
    for (int w = 0; w < 8; ++w) { st += sA[w][4*kg+i]; sst += ssA[w][4*kg+i]; }
    mu[i] = st*(1.f/160.f);
    float var = sst*(1.f/160.f) - mu[i]*mu[i];
    rs[i] = rsqrtf(var + 1e-5f);
  }
#pragma unroll
  for (int u = 0; u < 2; ++u)
    if (u < ntP) {
      int n = wid + 8*u;
      int col = n*16 + r15;
      float gv = g1[col], bv = bt1[col];
#pragma unroll
      for (int i = 0; i < 4; ++i) {
        int row = 4*kg + i;
        int byte = row*384 + ((col*2) ^ ((row & 7) << 4));
        *(unsigned short*)(L1 + byte) = f2bf((pn[u][i] - mu[i])*rs[i]*gv + bv);
      }
    }
  __syncthreads();

  fx4 acc2[3];
#pragma unroll
  for (int u = 0; u < 3; ++u) acc2[u] = (fx4){0.f,0.f,0.f,0.f};
#pragma unroll
  for (int t = 0; t < 5; ++t) {
    short8v a2 = *(const short8v*)(const void*)(L1 + r15*384 + ((t*64 + kg*16) ^ ((r15 & 7) << 4)));
#pragma unroll
    for (int u = 0; u < 3; ++u)
      if (u < ntM) {
        int n = wid + 8*u;
        short8v bfr = *(const short8v*)(const void*)(w1 + (size_t)(n*16 + r15)*160 + t*32 + kg*8);
        acc2[u] = __builtin_amdgcn_mfma_f32_16x16x32_bf16(a2, bfr, acc2[u], 0, 0, 0);
      }
  }
#pragma unroll
  for (int u = 0; u < 3; ++u)
    if (u < ntM) {
      int n = wid + 8*u;
      int col = n*16 + r15;
      float bv = b1v[col];
#pragma unroll
      for (int i = 0; i < 4; ++i) {
        float v = gelu_f(acc2[u][i] + bv);
        int row = 4*kg + i;
        int byte = row*640 + ((col*2) ^ ((row & 7) << 4));
        *(unsigned short*)(L2 + byte) = f2bf(v);
      }
    }
  __syncthreads();

  fx4 acc3[2];
#pragma unroll
  for (int u = 0; u < 2; ++u) acc3[u] = (fx4){0.f,0.f,0.f,0.f};
#pragma unroll
  for (int t = 0; t < 10; ++t) {
    short8v a3 = *(const short8v*)(const void*)(L2 + r15*640 + ((t*64 + kg*16) ^ ((r15 & 7) << 4)));
#pragma unroll
    for (int u = 0; u < 2; ++u)
      if (u < ntP) {
        int n = wid + 8*u;
        short8v bfr = *(const short8v*)(const void*)(w2 + (size_t)(n*16 + r15)*320 + t*32 + kg*8);
        acc3[u] = __builtin_amdgcn_mfma_f32_16x16x32_bf16(a3, bfr, acc3[u], 0, 0, 0);
      }
  }
  float sv2[4] = {0,0,0,0}, ssv2[4] = {0,0,0,0};
  float fnv[2][4];
#pragma unroll
  for (int u = 0; u < 2; ++u)
    if (u < ntP) {
      int n = wid + 8*u;
      int col = n*16 + r15;
      float bv = b2v[col];
#pragma unroll
      for (int i = 0; i < 4; ++i) {
        float v = pn[u][i] + acc3[u][i] + bv;
        fnv[u][i] = v;
        pf[(size_t)(row0 + 4*kg + i)*DIMS_ + col] = v;
        sv2[i] += v; ssv2[i] += v*v;
      }
    }
  if (!HASNEXT) return;

#pragma unroll
  for (int i = 0; i < 4; ++i) {
    sv2[i] += __shfl_xor(sv2[i], 1, 16); ssv2[i] += __shfl_xor(ssv2[i], 1, 16);
    sv2[i] += __shfl_xor(sv2[i], 2, 16); ssv2[i] += __shfl_xor(ssv2[i], 2, 16);
    sv2[i] += __shfl_xor(sv2[i], 4, 16); ssv2[i] += __shfl_xor(ssv2[i], 4, 16);
    sv2[i] += __shfl_xor(sv2[i], 8, 16); ssv2[i] += __shfl_xor(ssv2[i], 8, 16);
  }
  __syncthreads();
  if (r15 == 0) {
#pragma unroll
    for (int i = 0; i < 4; ++i) { sA[wid][4*kg+i] = sv2[i]; ssA[wid][4*kg+i] = ssv2[i]; }
  }
  __syncthreads();
#pragma unroll
  for (int i = 0; i < 4; ++i) {
    float st = 0.f, sst = 0.f;
#pragma unroll
    for (int w = 0; w < 8; ++w) { st += sA[w][4*kg+i]; sst += ssA[w][4*kg+i]; }
    mu[i] = st*(1.f/160.f);
    float var = sst*(1.f/160.f) - mu[i]*mu[i];
    rs[i] = rsqrtf(var + 1e-5f);
  }
#pragma unroll
  for (int u = 0; u < 2; ++u)
    if (u < ntP) {
      int n = wid + 8*u;
      int col = n*16 + r15;
      float gv = gn[col], bv = btn[col];
#pragma unroll
      for (int i = 0; i < 4; ++i) {
        int row = 4*kg + i;
        int byte = row*384 + ((col*2) ^ ((row & 7) << 4));
        *(unsigned short*)(L1 + byte) = f2bf((fnv[u][i] - mu[i])*rs[i]*gv + bv);
      }
    }
  __syncthreads();

  qkv_from_L1(L1, wqkvN, bqkvN, qbN, TRANSV_NEXT, row0, wid, r15, kg);
}

// ---------------- first QKV for fallback path ----------------
__global__ __launch_bounds__(512)
void qkv0_kernel(const unsigned short* __restrict__ xn,
                 const unsigned short* __restrict__ wt_attn, const float* __restrict__ attn_b,
                 unsigned short* __restrict__ qbA) {
  __shared__ unsigned short L1s[16*192];
  char* L1 = (char*)L1s;
  int tid = threadIdx.x;
  int wid = tid >> 6, lane = tid & 63;
  int r15 = lane & 15, kg = lane >> 4;
  int row0 = blockIdx.x * 16;
  for (int k = tid; k < 16*DIMS_; k += 512) {
    int row = k / DIMS_, col = k - row*DIMS_;
    int byte = row*384 + ((col*2) ^ ((row & 7) << 4));
    *(unsigned short*)(L1 + byte) = xn[(size_t)(row0 + row)*DIMS_ + col];
  }
  __syncthreads();
  qkv_from_L1(L1, wt_attn, attn_b, qbA, true, row0, wid, r15, kg);
}

// ---------------- final projection (fallback path only) ----------------
__global__ __launch_bounds__(256)
void out_kernel(const float* __restrict__ pf, const float* __restrict__ outW,
                const float* __restrict__ outB, const int* __restrict__ pk,
                float* __restrict__ out) {
  int idx = blockIdx.x*256 + threadIdx.x;
  if (idx >= BB*12*NNODES) return;
  int n = idx % NNODES;
  int rest = idx / NNODES;
  int o = rest % 12;
  int b = rest / 12;
  int row = b*PBB + pk[n];
  const float4* Pr = (const float4*)&pf[(size_t)row*DIMS_];
  const float4* Wr = (const float4*)&outW[o*DIMS_];
  float ax=0.f, ay=0.f, az=0.f, aw=0.f;
#pragma unroll
  for (int d4 = 0; d4 < 40; ++d4) {
    float4 a = Pr[d4], c = Wr[d4];
    ax += a.x*c.x; ay += a.y*c.y; az += a.z*c.z; aw += a.w*c.w;
  }
  out[idx] = (ax+ay+az+aw) + outB[o];
}

extern "C" void kernel_launch(void* const* d_in, const int* in_sizes, int n_in,
                              void* d_out, int out_size, void* d_ws, size_t ws_size,
                              hipStream_t stream) {
  const float* x         = (const float*)d_in[0];
  const int*   te        = (const int*)d_in[1];
  const float* patch_emb = (const float*)d_in[2];
  const float* node_tab  = (const float*)d_in[3];
  const float* tod_emb   = (const float*)d_in[4];
  const float* dow_emb   = (const float*)d_in[5];
  const float* conv_W    = (const float*)d_in[6];
  const float* conv_b    = (const float*)d_in[7];
  const float* ln_scale  = (const float*)d_in[8];
  const float* ln_bias   = (const float*)d_in[9];
  const float* attn_W    = (const float*)d_in[10];
  const float* attn_b    = (const float*)d_in[11];
  const float* mlp_W1    = (const float*)d_in[12];
  const float* mlp_b1    = (const float*)d_in[13];
  const float* mlp_W2    = (const float*)d_in[14];
  const float* mlp_b2    = (const float*)d_in[15];
  const float* out_W     = (const float*)d_in[16];
  const float* out_b     = (const float*)d_in[17];

  float* out = (float*)d_out;
  float* probs_st = out + BB*12*NNODES;

  const size_t CY = (size_t)(RMAX2 + 16) * DIMS_;        // q/k/v slice stride (ushorts)
  const size_t QBSZ = 2*CY + (size_t)DIMS_*RMAXP;        // one q/k/vt buffer (ushorts)

  char* W = (char*)d_ws;
  float* pf = (float*)W;                        W += (size_t)(RMAX2 + 16)*DIMS_*4;
  unsigned short* xn = (unsigned short*)W;      W += (size_t)(RMAX2 + 16)*DIMS_*2;
  unsigned short* qbA = (unsigned short*)W;     W += QBSZ*2;
  unsigned short* qbB = (unsigned short*)W;     W += QBSZ*2;
  unsigned short* wt_attn = (unsigned short*)W; W += (size_t)24*160*160*2;
  unsigned short* wt_w1   = (unsigned short*)W; W += (size_t)6*320*160*2;
  unsigned short* wt_w2   = (unsigned short*)W; W += (size_t)6*160*320*2;
  float* nsoft = (float*)W;                     W += (size_t)NNODES*32*4;
  int* flags = (int*)W;                         W += (size_t)6*GXNUM*4;
  int* invp  = (int*)W;                         W += (size_t)PBB*4;
  int* pk   = (int*)W;
  int* cnt  = pk + NNODES;
  int* offs = cnt + 8;

  {
    int n4 = (RMAX2 + 16) * DIMS_ / 4;
    zero_pf<<<(n4 + 255)/256, 256, 0, stream>>>((float4*)pf, n4);
  }
  zero_flags<<<(6*GXNUM + 255)/256, 256, 0, stream>>>(flags, 6*GXNUM);
  cvt_all<<<dim3(50, 36), 256, 0, stream>>>(attn_W, mlp_W1, mlp_W2, wt_attn, wt_w1, wt_w2);
  patch_scan<<<1, 1024, 0, stream>>>(node_tab, patch_emb, probs_st, nsoft, pk, cnt, offs, invp);
  embed_kernel<<<dim3(NNODES, BB), 160, 0, stream>>>(x, te, conv_W, conv_b, tod_emb, dow_emb,
                                                     nsoft, pk, ln_scale, ln_bias, pf, xn);

  // try cooperative persistent path (co-residency guarantee for spin-waits)
  int maxb = 0;
  hipError_t occ = hipOccupancyMaxActiveBlocksPerMultiprocessor(&maxb, (const void*)layers_coop, 512, 0);
  bool coop_ok = (occ == hipSuccess) && (maxb * 256 >= GXNUM);

  if (coop_ok) {
    void* args[] = {(void*)&qbA, (void*)&qbB, (void*)&wt_attn, (void*)&wt_w1, (void*)&wt_w2,
                    (void*)&attn_b, (void*)&mlp_b1, (void*)&mlp_b2,
                    (void*)&ln_scale, (void*)&ln_bias, (void*)&xn, (void*)&pf,
                    (void*)&cnt, (void*)&offs, (void*)&flags, (void*)&invp,
                    (void*)&out_W, (void*)&out_b, (void*)&out};
    hipError_t e = hipLaunchCooperativeKernel((const void*)layers_coop,
                                              dim3(GXNUM), dim3(512), args, 0, stream);
    coop_ok = (e == hipSuccess);
  }

  if (!coop_ok) {
    // fallback: per-layer launches with double-buffered QKV
    qkv0_kernel<<<GXNUM, 512, 0, stream>>>(xn, wt_attn, attn_b, qbA);
    for (int wb = 0; wb < 6; ++wb) {
      unsigned short* qbCur = (wb & 1) ? qbB : qbA;
      unsigned short* qbNext = (wb & 1) ? qbA : qbB;
      const unsigned short* wqkv = wt_attn + (size_t)wb*4*25600;
      const float* bbase = attn_b + (size_t)wb*4*DIMS_;
      const unsigned short* wproj = wqkv + 3*25600;
      const float* bproj = bbase + 3*DIMS_;
      const unsigned short* w1 = wt_w1 + (size_t)wb*51200;
      const unsigned short* w2 = wt_w2 + (size_t)wb*51200;
      const float* b1v = mlp_b1 + (size_t)wb*HID_;
      const float* b2v = mlp_b2 + (size_t)wb*DIMS_;
      const float* g1  = ln_scale + (size_t)(2*wb + 1)*DIMS_;
      const float* bt1 = ln_bias  + (size_t)(2*wb + 1)*DIMS_;
      const float* gn  = ln_scale + (size_t)(2*wb + 2)*DIMS_;
      const float* btn = ln_bias  + (size_t)(2*wb + 2)*DIMS_;
      const unsigned short* wqkvN = wt_attn + (size_t)(wb+1)*4*25600;
      const float* bqkvN = attn_b + (size_t)(wb+1)*4*DIMS_;
      if (wb == 5)
        fused_layer<false,false,false><<<GXNUM, 512, 0, stream>>>(
            qbCur, qbCur + CY, qbCur + 2*CY, wproj, bproj, w1, b1v, w2, b2v,
            g1, bt1, nullptr, nullptr, nullptr, nullptr, pf, qbNext, cnt, offs);
      else if ((wb & 1) == 0)
        fused_layer<true,true,false><<<GXNUM, 512, 0, stream>>>(
            qbCur, qbCur + CY, qbCur + 2*CY, wproj, bproj, w1, b1v, w2, b2v,
            g1, bt1, gn, btn, wqkvN, bqkvN, pf, qbNext, cnt, offs);
      else
        fused_layer<false,true,true><<<GXNUM, 512, 0, stream>>>(
            qbCur, qbCur + CY, qbCur + 2*CY, wproj, bproj, w1, b1v, w2, b2v,
            g1, bt1, gn, btn, wqkvN, bqkvN, pf, qbNext, cnt, offs);
    }
    out_kernel<<<(BB*12*NNODES + 255)/256, 256, 0, stream>>>(pf, out_W, out_b, pk, out);
  }
}